// Round 5
// baseline (176.607 us; speedup 1.0000x reference)
//
#include <hip/hip_runtime.h>

#define EPSF 1e-20f

__device__ __forceinline__ float frcp(float x) { return __builtin_amdgcn_rcpf(x); }

// ===========================================================================
// Pipeline in (U, c) representation, U = x*c.
//   nconv: den = conv(c); nom = conv(U); x = nom/(den+eps)+b; c' = den/sum(w);
//          U' = x*c'.
//   maxpool (argmax over c, torch first-max): U' = U_sel/4, c' = c_max/4.
//   up2: replicate (fused as half-res reads).
//   final 1x1: out = (w0*U0+w1*U1)/(w0*c0+w1*c1+eps)+b ; cout = den/(w0+w1).
// ===========================================================================

// ===========================================================================
// NEW CORE: 2-row x 4-col register-blocked nconv, K=5. Tile 64x32, 256 thr.
// LDS: [CIN][36][80] per tensor, cols [-8,72) vs tile, rows [-2,34).
// Conflict-free: quad = (4(j&1) + tx + c) mod 8 -> 8 lanes/quad exactly.
// ===========================================================================
template<int CIN, int LOGHW, bool IN_IS_U, bool POOL>
__global__ __launch_bounds__(256)
void nconv_blk(const float* __restrict__ xin, const float* __restrict__ cin_,
               const float* __restrict__ wgt, const float* __restrict__ bias,
               float* __restrict__ uout, float* __restrict__ cout,
               float* __restrict__ poolU, float* __restrict__ poolC)
{
    constexpr int HW = 1 << LOGHW;
    constexpr int ROWS = 36;
    constexpr int CHK = 20;
    __shared__ __align__(16) float s_d[CIN][ROWS][80];
    __shared__ __align__(16) float s_c[CIN][ROWS][80];

    const int tid = threadIdx.x;
    const int bw = blockIdx.x * 64;
    const int bh = blockIdx.y * 32;
    const int b  = blockIdx.z;

    const float4* x4 = (const float4*)xin;
    const float4* c4 = (const float4*)cin_;
    constexpr int SLOTS = CIN * ROWS * CHK;
    for (int i = tid; i < SLOTS; i += 256) {
        const int ci = i / (ROWS * CHK);
        const int r  = (i / CHK) % ROWS;
        const int k  = i % CHK;
        const int gh = bh - 2 + r;
        const int gw4 = (bw >> 2) - 2 + k;
        float4 dd = make_float4(0.f, 0.f, 0.f, 0.f);
        float4 cc = make_float4(0.f, 0.f, 0.f, 0.f);
        if ((unsigned)gh < (unsigned)HW && (unsigned)gw4 < (unsigned)(HW >> 2)) {
            const int a = ((b * CIN + ci) << (2 * LOGHW - 2)) + (gh << (LOGHW - 2)) + gw4;
            const float4 xx = x4[a];
            cc = c4[a];
            if (IN_IS_U) dd = xx;
            else dd = make_float4(xx.x * cc.x, xx.y * cc.y, xx.z * cc.z, xx.w * cc.w);
        }
        *(float4*)&s_d[ci][r][4 * k] = dd;
        *(float4*)&s_c[ci][r][4 * k] = cc;
    }
    __syncthreads();

    const int tx = tid & 15;      // 4-col group
    const int ty = tid >> 4;      // 2-row group (0..15)

    float den[2][2][4], nom[2][2][4];   // [co][orow][px]
    #pragma unroll
    for (int co = 0; co < 2; ++co)
        #pragma unroll
        for (int o = 0; o < 2; ++o)
            #pragma unroll
            for (int p = 0; p < 4; ++p) { den[co][o][p] = 0.f; nom[co][o][p] = 0.f; }

    #pragma unroll
    for (int j = 0; j < 6; ++j) {
        const int lr = 2 * ty + j;
        #pragma unroll
        for (int ci = 0; ci < CIN; ++ci) {
            float wd[12], wc[12];
            #pragma unroll
            for (int c = 0; c < 3; ++c) {
                const float4 t = *(const float4*)&s_d[ci][lr][4 * (tx + 1 + c)];
                wd[4*c] = t.x; wd[4*c+1] = t.y; wd[4*c+2] = t.z; wd[4*c+3] = t.w;
                const float4 u = *(const float4*)&s_c[ci][lr][4 * (tx + 1 + c)];
                wc[4*c] = u.x; wc[4*c+1] = u.y; wc[4*c+2] = u.z; wc[4*c+3] = u.w;
            }
            #pragma unroll
            for (int orow = 0; orow < 2; ++orow) {
                const int kh = j - orow;
                if (kh < 0 || kh > 4) continue;
                #pragma unroll
                for (int kw = 0; kw < 5; ++kw) {
                    const float w0 = wgt[((0 * CIN + ci) * 5 + kh) * 5 + kw];
                    const float w1 = wgt[((1 * CIN + ci) * 5 + kh) * 5 + kw];
                    #pragma unroll
                    for (int p = 0; p < 4; ++p) {
                        const int m = p + kw + 2;
                        den[0][orow][p] = fmaf(w0, wc[m], den[0][orow][p]);
                        nom[0][orow][p] = fmaf(w0, wd[m], nom[0][orow][p]);
                        den[1][orow][p] = fmaf(w1, wc[m], den[1][orow][p]);
                        nom[1][orow][p] = fmaf(w1, wd[m], nom[1][orow][p]);
                    }
                }
            }
        }
    }

    // epilogue: den <- cv, nom <- U'
    #pragma unroll
    for (int co = 0; co < 2; ++co) {
        float s = 0.f;
        for (int i = 0; i < CIN * 25; ++i) s += wgt[co * CIN * 25 + i];
        const float is = 1.0f / s;
        const float bb = bias[co];
        #pragma unroll
        for (int o = 0; o < 2; ++o)
            #pragma unroll
            for (int p = 0; p < 4; ++p) {
                const float xo = nom[co][o][p] * frcp(den[co][o][p] + EPSF) + bb;
                const float cv = den[co][o][p] * is;
                den[co][o][p] = cv;
                nom[co][o][p] = xo * cv;
            }
    }

    #pragma unroll
    for (int co = 0; co < 2; ++co)
        #pragma unroll
        for (int o = 0; o < 2; ++o) {
            const int a = ((b * 2 + co) << (2 * LOGHW - 2))
                        + ((bh + 2 * ty + o) << (LOGHW - 2)) + (bw >> 2) + tx;
            ((float4*)uout)[a] = make_float4(nom[co][o][0], nom[co][o][1], nom[co][o][2], nom[co][o][3]);
            ((float4*)cout)[a] = make_float4(den[co][o][0], den[co][o][1], den[co][o][2], den[co][o][3]);
        }

    if (POOL) {
        // in-register 2x2 pool (first-max on c): thread owns exactly 1x2 pooled px
        #pragma unroll
        for (int co = 0; co < 2; ++co) {
            float pg[2], pm[2];
            #pragma unroll
            for (int pc = 0; pc < 2; ++pc) {
                float m = den[co][0][2*pc],     g = nom[co][0][2*pc];
                if (den[co][0][2*pc+1] > m) { m = den[co][0][2*pc+1]; g = nom[co][0][2*pc+1]; }
                if (den[co][1][2*pc]   > m) { m = den[co][1][2*pc];   g = nom[co][1][2*pc]; }
                if (den[co][1][2*pc+1] > m) { m = den[co][1][2*pc+1]; g = nom[co][1][2*pc+1]; }
                pg[pc] = g * 0.25f;
                pm[pc] = m * 0.25f;
            }
            const int pa = ((b * 2 + co) << (2 * (LOGHW - 1)))
                         + (((bh >> 1) + ty) << (LOGHW - 1)) + (bw >> 1) + 2 * tx;
            *(float2*)&poolU[pa] = make_float2(pg[0], pg[1]);
            *(float2*)&poolC[pa] = make_float2(pm[0], pm[1]);
        }
    }
}

// ===========================================================================
// NEW cat core: 2x4-blocked nconv over concat(skip @full, up2(low @half)),
// K=3. Tile 64x32. Low channels staged at half res. Optional fused final 1x1.
// ===========================================================================
template<bool UP_FIRST, int LOGHW, bool FINAL>
__global__ __launch_bounds__(256)
void cat_blk(const float* __restrict__ skU, const float* __restrict__ skC,
             const float* __restrict__ loU, const float* __restrict__ loC,
             const float* __restrict__ wgt, const float* __restrict__ bias,
             float* __restrict__ uout, float* __restrict__ cout,
             const float* __restrict__ w7, const float* __restrict__ b7)
{
    constexpr int HW = 1 << LOGHW;
    constexpr int HWL = HW >> 1;
    constexpr int SK0 = UP_FIRST ? 2 : 0;
    constexpr int LO0 = UP_FIRST ? 0 : 2;
    __shared__ __align__(16) float s_d[2][34][80],  s_c[2][34][80];
    __shared__ __align__(16) float lo_d[2][18][40], lo_c[2][18][40];

    const int tid = threadIdx.x;
    const int bw = blockIdx.x * 64;
    const int bh = blockIdx.y * 32;
    const int b  = blockIdx.z;

    const float4* sU4 = (const float4*)skU;
    const float4* sC4 = (const float4*)skC;
    for (int i = tid; i < 2 * 34 * 20; i += 256) {
        const int ci = i / (34 * 20);
        const int r  = (i / 20) % 34;
        const int k  = i % 20;
        const int gh = bh - 1 + r;
        const int gw4 = (bw >> 2) - 2 + k;
        float4 dd = make_float4(0.f, 0.f, 0.f, 0.f);
        float4 cc = make_float4(0.f, 0.f, 0.f, 0.f);
        if ((unsigned)gh < (unsigned)HW && (unsigned)gw4 < (unsigned)(HW >> 2)) {
            const int a = ((b * 2 + ci) << (2 * LOGHW - 2)) + (gh << (LOGHW - 2)) + gw4;
            dd = sU4[a];
            cc = sC4[a];
        }
        *(float4*)&s_d[ci][r][4 * k] = dd;
        *(float4*)&s_c[ci][r][4 * k] = cc;
    }
    const float4* lU4 = (const float4*)loU;
    const float4* lC4 = (const float4*)loC;
    for (int i = tid; i < 2 * 18 * 10; i += 256) {
        const int ci = i / 180;
        const int r  = (i / 10) % 18;
        const int k  = i % 10;
        const int gr = (bh >> 1) - 1 + r;
        const int gc4 = (bw >> 3) - 1 + k;
        float4 dd = make_float4(0.f, 0.f, 0.f, 0.f);
        float4 cc = make_float4(0.f, 0.f, 0.f, 0.f);
        if ((unsigned)gr < (unsigned)HWL && (unsigned)gc4 < (unsigned)(HWL >> 2)) {
            const int a = ((b * 2 + ci) << (2 * (LOGHW - 1) - 2)) + (gr << (LOGHW - 3)) + gc4;
            dd = lU4[a];
            cc = lC4[a];
        }
        *(float4*)&lo_d[ci][r][4 * k] = dd;
        *(float4*)&lo_c[ci][r][4 * k] = cc;
    }
    __syncthreads();

    const int tx = tid & 15;
    const int ty = tid >> 4;

    float den[2][2][4], nom[2][2][4];
    #pragma unroll
    for (int co = 0; co < 2; ++co)
        #pragma unroll
        for (int o = 0; o < 2; ++o)
            #pragma unroll
            for (int p = 0; p < 4; ++p) { den[co][o][p] = 0.f; nom[co][o][p] = 0.f; }

    // ---- skip channels (full res), K=3: LDS row lr = 2ty+j <-> tile row lr-1
    #pragma unroll
    for (int j = 0; j < 4; ++j) {
        const int lr = 2 * ty + j;
        #pragma unroll
        for (int ci = 0; ci < 2; ++ci) {
            float wd[12], wc[12];
            #pragma unroll
            for (int c = 0; c < 3; ++c) {
                const float4 t = *(const float4*)&s_d[ci][lr][4 * (tx + 1 + c)];
                wd[4*c] = t.x; wd[4*c+1] = t.y; wd[4*c+2] = t.z; wd[4*c+3] = t.w;
                const float4 u = *(const float4*)&s_c[ci][lr][4 * (tx + 1 + c)];
                wc[4*c] = u.x; wc[4*c+1] = u.y; wc[4*c+2] = u.z; wc[4*c+3] = u.w;
            }
            #pragma unroll
            for (int orow = 0; orow < 2; ++orow) {
                const int kh = j - orow;
                if (kh < 0 || kh > 2) continue;
                #pragma unroll
                for (int kw = 0; kw < 3; ++kw) {
                    const float w0 = wgt[((0 * 4 + SK0 + ci) * 3 + kh) * 3 + kw];
                    const float w1 = wgt[((1 * 4 + SK0 + ci) * 3 + kh) * 3 + kw];
                    #pragma unroll
                    for (int p = 0; p < 4; ++p) {
                        const int m = p + kw + 3;
                        den[0][orow][p] = fmaf(w0, wc[m], den[0][orow][p]);
                        nom[0][orow][p] = fmaf(w0, wd[m], nom[0][orow][p]);
                        den[1][orow][p] = fmaf(w1, wc[m], den[1][orow][p]);
                        nom[1][orow][p] = fmaf(w1, wd[m], nom[1][orow][p]);
                    }
                }
            }
        }
    }

    // ---- low channels (half res, replicated): LDS low row = ty + jl
    #pragma unroll
    for (int jl = 0; jl < 3; ++jl) {
        const int lrow = ty + jl;
        #pragma unroll
        for (int ci = 0; ci < 2; ++ci) {
            float wld[6], wlc[6];
            #pragma unroll
            for (int i2 = 0; i2 < 3; ++i2) {
                const float2 t = *(const float2*)&lo_d[ci][lrow][2 * tx + 2 + 2 * i2];
                wld[2*i2] = t.x; wld[2*i2+1] = t.y;
                const float2 u = *(const float2*)&lo_c[ci][lrow][2 * tx + 2 + 2 * i2];
                wlc[2*i2] = u.x; wlc[2*i2+1] = u.y;
            }
            #pragma unroll
            for (int orow = 0; orow < 2; ++orow)
                #pragma unroll
                for (int khp = 0; khp < 3; ++khp) {
                    const int need_jl = (orow == 0) ? (khp == 0 ? 0 : 1)
                                                    : (khp == 2 ? 2 : 1);
                    if (need_jl != jl) continue;
                    #pragma unroll
                    for (int kwp = 0; kwp < 3; ++kwp) {
                        const float w0 = wgt[((0 * 4 + LO0 + ci) * 3 + khp) * 3 + kwp];
                        const float w1 = wgt[((1 * 4 + LO0 + ci) * 3 + khp) * 3 + kwp];
                        #pragma unroll
                        for (int p = 0; p < 4; ++p) {
                            const int t = p + kwp - 1;
                            const int m = ((t < 0) ? -1 : (t >> 1)) + 2;
                            den[0][orow][p] = fmaf(w0, wlc[m], den[0][orow][p]);
                            nom[0][orow][p] = fmaf(w0, wld[m], nom[0][orow][p]);
                            den[1][orow][p] = fmaf(w1, wlc[m], den[1][orow][p]);
                            nom[1][orow][p] = fmaf(w1, wld[m], nom[1][orow][p]);
                        }
                    }
                }
        }
    }

    // epilogue
    #pragma unroll
    for (int co = 0; co < 2; ++co) {
        float s = 0.f;
        for (int i = 0; i < 36; ++i) s += wgt[co * 36 + i];
        const float is = 1.0f / s;
        const float bb = bias[co];
        #pragma unroll
        for (int o = 0; o < 2; ++o)
            #pragma unroll
            for (int p = 0; p < 4; ++p) {
                const float xo = nom[co][o][p] * frcp(den[co][o][p] + EPSF) + bb;
                const float cv = den[co][o][p] * is;
                den[co][o][p] = cv;
                nom[co][o][p] = xo * cv;
            }
    }

    if (FINAL) {
        const float w70 = w7[0], w71 = w7[1], bb7 = b7[0];
        const float inv = frcp(w70 + w71);
        #pragma unroll
        for (int o = 0; o < 2; ++o) {
            float4 xo4, cc4;
            #pragma unroll
            for (int p = 0; p < 4; ++p) {
                const float d1 = w70 * den[0][o][p] + w71 * den[1][o][p];
                (&xo4.x)[p] = (w70 * nom[0][o][p] + w71 * nom[1][o][p]) * frcp(d1 + EPSF) + bb7;
                (&cc4.x)[p] = d1 * inv;
            }
            const int a = (b << (2 * LOGHW - 2)) + ((bh + 2 * ty + o) << (LOGHW - 2)) + (bw >> 2) + tx;
            ((float4*)uout)[a] = xo4;
            ((float4*)uout)[(1 << 19) + a] = cc4;
        }
    } else {
        #pragma unroll
        for (int co = 0; co < 2; ++co)
            #pragma unroll
            for (int o = 0; o < 2; ++o) {
                const int a = ((b * 2 + co) << (2 * LOGHW - 2))
                            + ((bh + 2 * ty + o) << (LOGHW - 2)) + (bw >> 2) + tx;
                ((float4*)uout)[a] = make_float4(nom[co][o][0], nom[co][o][1], nom[co][o][2], nom[co][o][3]);
                ((float4*)cout)[a] = make_float4(den[co][o][0], den[co][o][1], den[co][o][2], den[co][o][3]);
            }
    }
}

// ===========================================================================
// OLD small-res kernels (proven): conv_core/conv_low/nconv_tiled/cat_tiled
// ===========================================================================
template<int NCI, int CI0, int CINT, int K, int ROWS>
__device__ __forceinline__ void conv_core(const float* __restrict__ s_d,
                                          const float* __restrict__ s_c,
                                          const float* __restrict__ wgt,
                                          int lh, int lw,
                                          float den[2][4], float nom[2][4])
{
    constexpr int JOFF = 4 - (K / 2);
    #pragma unroll
    for (int kh = 0; kh < K; ++kh) {
        #pragma unroll
        for (int ci = 0; ci < NCI; ++ci) {
            const float4* rd = (const float4*)(s_d + (ci * ROWS + lh + kh) * 72 + lw);
            const float4* rc = (const float4*)(s_c + (ci * ROWS + lh + kh) * 72 + lw);
            float wd[12], wc[12];
            #pragma unroll
            for (int q = 0; q < 3; ++q) {
                const float4 t = rd[q];
                wd[4*q] = t.x; wd[4*q+1] = t.y; wd[4*q+2] = t.z; wd[4*q+3] = t.w;
                const float4 u = rc[q];
                wc[4*q] = u.x; wc[4*q+1] = u.y; wc[4*q+2] = u.z; wc[4*q+3] = u.w;
            }
            #pragma unroll
            for (int kw = 0; kw < K; ++kw) {
                const float w0 = wgt[((0 * CINT + CI0 + ci) * K + kh) * K + kw];
                const float w1 = wgt[((1 * CINT + CI0 + ci) * K + kh) * K + kw];
                #pragma unroll
                for (int p = 0; p < 4; ++p) {
                    const int j = p + kw + JOFF;
                    den[0][p] = fmaf(w0, wc[j], den[0][p]);
                    nom[0][p] = fmaf(w0, wd[j], nom[0][p]);
                    den[1][p] = fmaf(w1, wc[j], den[1][p]);
                    nom[1][p] = fmaf(w1, wd[j], nom[1][p]);
                }
            }
        }
    }
}

template<int LO0>
__device__ __forceinline__ void conv_low(const float* __restrict__ s_lo_d,
                                         const float* __restrict__ s_lo_c,
                                         const float* __restrict__ wgt,
                                         int lh, int lw,
                                         float den[2][4], float nom[2][4])
{
    #pragma unroll
    for (int kh = 0; kh < 3; ++kh) {
        const int rel_r = ((lh + kh - 1) >> 1) + 1;
        #pragma unroll
        for (int lci = 0; lci < 2; ++lci) {
            const float* rd = s_lo_d + (lci * 10 + rel_r) * 40 + (lw >> 1) + 2;
            const float* rc = s_lo_c + (lci * 10 + rel_r) * 40 + (lw >> 1) + 2;
            float wd[6], wc[6];
            #pragma unroll
            for (int q = 0; q < 3; ++q) {
                const float2 t = *(const float2*)(rd + 2 * q);
                wd[2*q] = t.x; wd[2*q+1] = t.y;
                const float2 u = *(const float2*)(rc + 2 * q);
                wc[2*q] = u.x; wc[2*q+1] = u.y;
            }
            #pragma unroll
            for (int kw = 0; kw < 3; ++kw) {
                const float w0 = wgt[((0 * 4 + LO0 + lci) * 3 + kh) * 3 + kw];
                const float w1 = wgt[((1 * 4 + LO0 + lci) * 3 + kh) * 3 + kw];
                #pragma unroll
                for (int p = 0; p < 4; ++p) {
                    const int t = p + kw - 1;
                    const int jl = ((t < 0) ? -1 : (t >> 1)) + 2;
                    den[0][p] = fmaf(w0, wc[jl], den[0][p]);
                    nom[0][p] = fmaf(w0, wd[jl], nom[0][p]);
                    den[1][p] = fmaf(w1, wc[jl], den[1][p]);
                    nom[1][p] = fmaf(w1, wd[jl], nom[1][p]);
                }
            }
        }
    }
}

template<int CINT, int K>
__device__ __forceinline__ void nconv_epilogue(const float* __restrict__ wgt,
                                               const float* __restrict__ bias,
                                               float den[2][4], float nom[2][4],
                                               float4 uo[2], float4 co4[2])
{
    #pragma unroll
    for (int c = 0; c < 2; ++c) {
        float s = 0.f;
        for (int i = 0; i < CINT * K * K; ++i) s += wgt[c * CINT * K * K + i];
        const float is = 1.0f / s;
        const float bb = bias[c];
        #pragma unroll
        for (int p = 0; p < 4; ++p) {
            const float xo = nom[c][p] * frcp(den[c][p] + EPSF) + bb;
            const float cv = den[c][p] * is;
            (&co4[c].x)[p] = cv;
            (&uo[c].x)[p]  = xo * cv;
        }
    }
}

template<int CIN, int K, int LOGHW, bool IN_IS_U, bool POOL>
__global__ __launch_bounds__(256)
void nconv_tiled(const float* __restrict__ xin, const float* __restrict__ cin_,
                 const float* __restrict__ wgt, const float* __restrict__ bias,
                 float* __restrict__ uout, float* __restrict__ cout,
                 float* __restrict__ poolU, float* __restrict__ poolC)
{
    constexpr int HW = 1 << LOGHW;
    constexpr int PAD = K / 2;
    constexpr int TH = 16;
    constexpr int ROWS = TH + 2 * PAD;
    constexpr int NC4 = 18;
    __shared__ __align__(16) float s_d[CIN][ROWS][72];
    __shared__ __align__(16) float s_c[CIN][ROWS][72];

    const int tid = threadIdx.x;
    const int base_w = blockIdx.x * 64;
    const int base_h = blockIdx.y * TH;
    const int b = blockIdx.z;

    constexpr int SLOTS = CIN * ROWS * NC4;
    const float4* x4 = (const float4*)xin;
    const float4* c4p = (const float4*)cin_;
    for (int i = tid; i < SLOTS; i += 256) {
        const int ci = i / (ROWS * NC4);
        const int r  = (i / NC4) % ROWS;
        const int cf = i % NC4;
        const int gh = base_h - PAD + r;
        const int gw4 = (base_w >> 2) + cf - 1;
        float4 dd = make_float4(0.f, 0.f, 0.f, 0.f);
        float4 cc = make_float4(0.f, 0.f, 0.f, 0.f);
        if ((unsigned)gh < (unsigned)HW && (unsigned)gw4 < (unsigned)(HW >> 2)) {
            const int a = ((b * CIN + ci) << (2 * LOGHW - 2)) + (gh << (LOGHW - 2)) + gw4;
            const float4 xx = x4[a];
            cc = c4p[a];
            if (IN_IS_U) dd = xx;
            else dd = make_float4(xx.x * cc.x, xx.y * cc.y, xx.z * cc.z, xx.w * cc.w);
        }
        *(float4*)&s_d[ci][r][cf * 4] = dd;
        *(float4*)&s_c[ci][r][cf * 4] = cc;
    }
    __syncthreads();

    const int lh = tid >> 4;
    const int lw = (tid & 15) << 2;
    float den[2][4], nom[2][4];
    #pragma unroll
    for (int c = 0; c < 2; ++c)
        #pragma unroll
        for (int p = 0; p < 4; ++p) { den[c][p] = 0.f; nom[c][p] = 0.f; }

    conv_core<CIN, 0, CIN, K, ROWS>(&s_d[0][0][0], &s_c[0][0][0], wgt, lh, lw, den, nom);

    float4 uo[2], co4[2];
    nconv_epilogue<CIN, K>(wgt, bias, den, nom, uo, co4);

    const int oh = base_h + lh;
    #pragma unroll
    for (int c = 0; c < 2; ++c) {
        const int a = ((b * 2 + c) << (2 * LOGHW - 2)) + (oh << (LOGHW - 2)) + ((base_w + lw) >> 2);
        ((float4*)uout)[a] = uo[c];
        ((float4*)cout)[a] = co4[c];
    }

    if (POOL) {
        __syncthreads();
        float* pu = &s_d[0][0][0];
        float* pcb = &s_c[0][0][0];
        #pragma unroll
        for (int c = 0; c < 2; ++c) {
            *(float4*)&pu[(c * 16 + lh) * 64 + lw] = uo[c];
            *(float4*)&pcb[(c * 16 + lh) * 64 + lw] = co4[c];
        }
        __syncthreads();
        #pragma unroll
        for (int rep = 0; rep < 2; ++rep) {
            const int o = tid + rep * 256;
            const int ch = o >> 8;
            const int idx = o & 255;
            const int pr = idx >> 5;
            const int pcc = idx & 31;
            const int bse = (ch * 16 + 2 * pr) * 64 + 2 * pcc;
            const float c00 = pcb[bse],      c01 = pcb[bse + 1];
            const float c10 = pcb[bse + 64], c11 = pcb[bse + 65];
            float m = c00; float g = pu[bse];
            if (c01 > m) { m = c01; g = pu[bse + 1]; }
            if (c10 > m) { m = c10; g = pu[bse + 64]; }
            if (c11 > m) { m = c11; g = pu[bse + 65]; }
            const int pa = ((b * 2 + ch) << (2 * (LOGHW - 1)))
                         + (((base_h >> 1) + pr) << (LOGHW - 1)) + (base_w >> 1) + pcc;
            poolU[pa] = g * 0.25f;
            poolC[pa] = m * 0.25f;
        }
    }
}

template<bool UP_FIRST, int LOGHW>
__global__ __launch_bounds__(256)
void nconv_cat_tiled(const float* __restrict__ skU, const float* __restrict__ skC,
                     const float* __restrict__ loU, const float* __restrict__ loC,
                     const float* __restrict__ wgt, const float* __restrict__ bias,
                     float* __restrict__ uout, float* __restrict__ cout)
{
    constexpr int HW = 1 << LOGHW;
    constexpr int HWL = HW >> 1;
    constexpr int TH = 16;
    constexpr int ROWS = TH + 2;
    constexpr int NC4 = 18;
    constexpr int SK0 = UP_FIRST ? 2 : 0;
    constexpr int LO0 = UP_FIRST ? 0 : 2;
    __shared__ __align__(16) float s_d[2][ROWS][72];
    __shared__ __align__(16) float s_c[2][ROWS][72];
    __shared__ __align__(16) float s_lo_d[2][10][40];
    __shared__ __align__(16) float s_lo_c[2][10][40];

    const int tid = threadIdx.x;
    const int base_w = blockIdx.x * 64;
    const int base_h = blockIdx.y * TH;
    const int b = blockIdx.z;

    constexpr int SLOTS = 2 * ROWS * NC4;
    const float4* sU4 = (const float4*)skU;
    const float4* sC4 = (const float4*)skC;
    for (int i = tid; i < SLOTS; i += 256) {
        const int ci = i / (ROWS * NC4);
        const int r  = (i / NC4) % ROWS;
        const int cf = i % NC4;
        const int gh = base_h - 1 + r;
        const int gw4 = (base_w >> 2) + cf - 1;
        float4 dd = make_float4(0.f, 0.f, 0.f, 0.f);
        float4 cc = make_float4(0.f, 0.f, 0.f, 0.f);
        if ((unsigned)gh < (unsigned)HW && (unsigned)gw4 < (unsigned)(HW >> 2)) {
            const int a = ((b * 2 + ci) << (2 * LOGHW - 2)) + (gh << (LOGHW - 2)) + gw4;
            dd = sU4[a];
            cc = sC4[a];
        }
        *(float4*)&s_d[ci][r][cf * 4] = dd;
        *(float4*)&s_c[ci][r][cf * 4] = cc;
    }
    constexpr int LO_SLOTS = 2 * 10 * 10;
    const int lo_r0 = (base_h >> 1) - 1;
    const int lo_c4_0 = (base_w >> 3) - 1;
    const float4* lU4 = (const float4*)loU;
    const float4* lC4 = (const float4*)loC;
    for (int i = tid; i < LO_SLOTS; i += 256) {
        const int ci = i / 100;
        const int r  = (i / 10) % 10;
        const int cf = i % 10;
        const int gr = lo_r0 + r;
        const int gc4 = lo_c4_0 + cf;
        float4 dd = make_float4(0.f, 0.f, 0.f, 0.f);
        float4 cc = make_float4(0.f, 0.f, 0.f, 0.f);
        if ((unsigned)gr < (unsigned)HWL && (unsigned)gc4 < (unsigned)(HWL >> 2)) {
            const int a = ((b * 2 + ci) << (2 * (LOGHW - 1) - 2)) + (gr << (LOGHW - 3)) + gc4;
            dd = lU4[a];
            cc = lC4[a];
        }
        *(float4*)&s_lo_d[ci][r][cf * 4] = dd;
        *(float4*)&s_lo_c[ci][r][cf * 4] = cc;
    }
    __syncthreads();

    const int lh = tid >> 4;
    const int lw = (tid & 15) << 2;
    float den[2][4], nom[2][4];
    #pragma unroll
    for (int c = 0; c < 2; ++c)
        #pragma unroll
        for (int p = 0; p < 4; ++p) { den[c][p] = 0.f; nom[c][p] = 0.f; }

    conv_core<2, SK0, 4, 3, ROWS>(&s_d[0][0][0], &s_c[0][0][0], wgt, lh, lw, den, nom);
    conv_low<LO0>(&s_lo_d[0][0][0], &s_lo_c[0][0][0], wgt, lh, lw, den, nom);

    float4 uo[2], co4[2];
    nconv_epilogue<4, 3>(wgt, bias, den, nom, uo, co4);

    const int oh = base_h + lh;
    #pragma unroll
    for (int c = 0; c < 2; ++c) {
        const int a = ((b * 2 + c) << (2 * LOGHW - 2)) + (oh << (LOGHW - 2)) + ((base_w + lw) >> 2);
        ((float4*)uout)[a] = uo[c];
        ((float4*)cout)[a] = co4[c];
    }
}

// ---------------------------------------------------------------------------
extern "C" void kernel_launch(void* const* d_in, const int* in_sizes, int n_in,
                              void* d_out, int out_size, void* d_ws, size_t ws_size,
                              hipStream_t stream) {
    (void)in_sizes; (void)n_in; (void)out_size; (void)ws_size;
    const float* x0 = (const float*)d_in[0];
    const float* c0 = (const float*)d_in[1];
    const float* w1 = (const float*)d_in[2];  const float* b1 = (const float*)d_in[3];
    const float* w2 = (const float*)d_in[4];  const float* b2 = (const float*)d_in[5];
    const float* w3 = (const float*)d_in[6];  const float* b3 = (const float*)d_in[7];
    const float* w4 = (const float*)d_in[8];  const float* b4 = (const float*)d_in[9];
    const float* w5 = (const float*)d_in[10]; const float* b5 = (const float*)d_in[11];
    const float* w6 = (const float*)d_in[12]; const float* b6 = (const float*)d_in[13];
    const float* w7 = (const float*)d_in[14]; const float* b7 = (const float*)d_in[15];

    float* ws = (float*)d_ws;
    const size_t S512 = 8ull * 2 * 512 * 512;
    const size_t S256 = 8ull * 2 * 256 * 256;
    const size_t S128 = 8ull * 2 * 128 * 128;
    const size_t S64  = 8ull * 2 * 64  * 64;

    float* X1x = ws;            float* X1c = ws + S512;
    float* Ax  = ws + 2 * S512; float* Ac  = ws + 3 * S512;
    float* Bx  = ws + 4 * S512; float* Bc  = ws + 5 * S512;
    float* x23x = Ax;               float* x23c = Ax + S256;
    float* x2x  = Ax + 2 * S256;    float* x2c  = Ax + 3 * S256;
    float* p1x  = Ax + 4 * S256;    float* p1c  = Ax + 5 * S256;
    float* qx   = Ax + 6 * S256;    float* qc   = Ax + 7 * S256;
    float* x3x  = Bx;               float* x3c  = Bx + S128;
    float* p2x  = Bx + 2 * S128;    float* p2c  = Bx + 3 * S128;
    float* x34x = Bx + 4 * S128;    float* x34c = Bx + 5 * S128;
    float* p3x  = Bx + 6 * S128;            float* p3c = Bx + 6 * S128 + S64;
    float* x4x  = Bx + 6 * S128 + 2 * S64;  float* x4c = Bx + 6 * S128 + 3 * S64;

    // Encoder @512 (new core)
    nconv_blk<1, 9, false, false><<<dim3(8, 16, 8), 256, 0, stream>>>(
        x0, c0, w1, b1, Ax, Ac, nullptr, nullptr);
    nconv_blk<2, 9, true, false><<<dim3(8, 16, 8), 256, 0, stream>>>(
        Ax, Ac, w2, b2, Bx, Bc, nullptr, nullptr);
    nconv_blk<2, 9, true, true><<<dim3(8, 16, 8), 256, 0, stream>>>(
        Bx, Bc, w3, b3, X1x, X1c, p1x, p1c);
    // @256 (new core)
    nconv_blk<2, 8, true, false><<<dim3(4, 8, 8), 256, 0, stream>>>(
        p1x, p1c, w2, b2, qx, qc, nullptr, nullptr);
    nconv_blk<2, 8, true, true><<<dim3(4, 8, 8), 256, 0, stream>>>(
        qx, qc, w3, b3, x2x, x2c, p2x, p2c);
    // @128 + pool, @64 (old core)
    nconv_tiled<2, 5, 7, true, true><<<dim3(2, 8, 8), 256, 0, stream>>>(
        p2x, p2c, w2, b2, x3x, x3c, p3x, p3c);
    nconv_tiled<2, 5, 6, true, false><<<dim3(1, 4, 8), 256, 0, stream>>>(
        p3x, p3c, w2, b2, x4x, x4c, nullptr, nullptr);
    // Decoder
    nconv_cat_tiled<false, 7><<<dim3(2, 8, 8), 256, 0, stream>>>(
        x3x, x3c, x4x, x4c, w4, b4, x34x, x34c);
    cat_blk<false, 8, false><<<dim3(4, 8, 8), 256, 0, stream>>>(
        x2x, x2c, x34x, x34c, w5, b5, x23x, x23c, nullptr, nullptr);
    cat_blk<true, 9, true><<<dim3(8, 16, 8), 256, 0, stream>>>(
        X1x, X1c, x23x, x23c, w6, b6, (float*)d_out, nullptr, w7, b7);
}

// Round 6
// 150.586 us; speedup vs baseline: 1.1728x; 1.1728x over previous
//
#include <hip/hip_runtime.h>

#define EPSF 1e-20f

__device__ __forceinline__ float frcp(float x) { return __builtin_amdgcn_rcpf(x); }

// ===========================================================================
// Pipeline in (U, c) representation, U = x*c.
//   nconv: den = conv(c); nom = conv(U); x = nom/(den+eps)+b; c' = den/sum(w);
//          U' = x*c'.
//   maxpool (argmax over c, torch first-max): U' = U_sel/4, c' = c_max/4.
//   up2: replicate (fused as half-res reads).
//   final 1x1: out = (w0*U0+w1*U1)/(w0*c0+w1*c1+eps)+b ; cout = den/(w0+w1).
// ===========================================================================

// ---------------------------------------------------------------------------
// One conv pass (K=5) over a single LDS tensor [CIN][36][80], accumulating
// 2 out-channels x 2 out-rows x 4 px. Explicit distance-1 prefetch pipeline:
// next group's 3 ds_read_b128 are issued before current group's ~80 FMAs.
// ---------------------------------------------------------------------------
template<int CIN>
__device__ __forceinline__ void conv_pass5(const float* __restrict__ s,
                                           const float* __restrict__ wgt,
                                           int tx, int ty,
                                           float acc[2][2][4])
{
    constexpr int NG = 6 * CIN;
    const float* base = s + (2 * ty) * 80 + 4 * (tx + 1);
    float4 A0, A1, A2, B0, B1, B2;
    {
        const float* p = base;              // g=0: j=0, ci=0
        A0 = *(const float4*)p; A1 = *(const float4*)(p + 4); A2 = *(const float4*)(p + 8);
    }
    #pragma unroll
    for (int g = 0; g < NG; ++g) {
        if (g + 1 < NG) {
            const int jn = (g + 1) / CIN, cin = (g + 1) % CIN;
            const float* p = base + (cin * 36 + jn) * 80;
            if ((g & 1) == 0) { B0 = *(const float4*)p; B1 = *(const float4*)(p + 4); B2 = *(const float4*)(p + 8); }
            else              { A0 = *(const float4*)p; A1 = *(const float4*)(p + 4); A2 = *(const float4*)(p + 8); }
        }
        float w[12];
        if ((g & 1) == 0) {
            w[0]=A0.x; w[1]=A0.y; w[2]=A0.z;  w[3]=A0.w;
            w[4]=A1.x; w[5]=A1.y; w[6]=A1.z;  w[7]=A1.w;
            w[8]=A2.x; w[9]=A2.y; w[10]=A2.z; w[11]=A2.w;
        } else {
            w[0]=B0.x; w[1]=B0.y; w[2]=B0.z;  w[3]=B0.w;
            w[4]=B1.x; w[5]=B1.y; w[6]=B1.z;  w[7]=B1.w;
            w[8]=B2.x; w[9]=B2.y; w[10]=B2.z; w[11]=B2.w;
        }
        const int j = g / CIN, ci = g % CIN;
        #pragma unroll
        for (int orow = 0; orow < 2; ++orow) {
            const int kh = j - orow;
            if (kh < 0 || kh > 4) continue;
            #pragma unroll
            for (int kw = 0; kw < 5; ++kw) {
                const float w0 = wgt[((0 * CIN + ci) * 5 + kh) * 5 + kw];
                const float w1 = wgt[((1 * CIN + ci) * 5 + kh) * 5 + kw];
                #pragma unroll
                for (int p4 = 0; p4 < 4; ++p4) {
                    const int m = p4 + kw + 2;
                    acc[0][orow][p4] = fmaf(w0, w[m], acc[0][orow][p4]);
                    acc[1][orow][p4] = fmaf(w1, w[m], acc[1][orow][p4]);
                }
            }
        }
    }
}

// ===========================================================================
// Register-blocked nconv, K=5. Tile 64x32, 256 thr, 8 px/thread.
// Split passes (den over c, nom over d) + explicit prefetch (conv_pass5).
// Optional fused in-register 2x2 maxpool.
// ===========================================================================
template<int CIN, int LOGHW, bool IN_IS_U, bool POOL>
__global__ __launch_bounds__(256, 3)
void nconv_rb(const float* __restrict__ xin, const float* __restrict__ cin_,
              const float* __restrict__ wgt, const float* __restrict__ bias,
              float* __restrict__ uout, float* __restrict__ cout,
              float* __restrict__ poolU, float* __restrict__ poolC)
{
    constexpr int HW = 1 << LOGHW;
    constexpr int ROWS = 36;
    constexpr int CHK = 20;
    __shared__ __align__(16) float s_d[CIN][ROWS][80];
    __shared__ __align__(16) float s_c[CIN][ROWS][80];

    const int tid = threadIdx.x;
    const int bw = blockIdx.x * 64;
    const int bh = blockIdx.y * 32;
    const int b  = blockIdx.z;

    const float4* x4 = (const float4*)xin;
    const float4* c4 = (const float4*)cin_;
    constexpr int SLOTS = CIN * ROWS * CHK;
    for (int i = tid; i < SLOTS; i += 256) {
        const int ci = i / (ROWS * CHK);
        const int r  = (i / CHK) % ROWS;
        const int k  = i % CHK;
        const int gh = bh - 2 + r;
        const int gw4 = (bw >> 2) - 2 + k;
        float4 dd = make_float4(0.f, 0.f, 0.f, 0.f);
        float4 cc = make_float4(0.f, 0.f, 0.f, 0.f);
        if ((unsigned)gh < (unsigned)HW && (unsigned)gw4 < (unsigned)(HW >> 2)) {
            const int a = ((b * CIN + ci) << (2 * LOGHW - 2)) + (gh << (LOGHW - 2)) + gw4;
            const float4 xx = x4[a];
            cc = c4[a];
            if (IN_IS_U) dd = xx;
            else dd = make_float4(xx.x * cc.x, xx.y * cc.y, xx.z * cc.z, xx.w * cc.w);
        }
        *(float4*)&s_d[ci][r][4 * k] = dd;
        *(float4*)&s_c[ci][r][4 * k] = cc;
    }
    __syncthreads();

    const int tx = tid & 15;      // 4-col group
    const int ty = tid >> 4;      // 2-row group (0..15)

    float den[2][2][4], nom[2][2][4];   // [co][orow][px]
    #pragma unroll
    for (int co = 0; co < 2; ++co)
        #pragma unroll
        for (int o = 0; o < 2; ++o)
            #pragma unroll
            for (int p = 0; p < 4; ++p) { den[co][o][p] = 0.f; nom[co][o][p] = 0.f; }

    conv_pass5<CIN>(&s_c[0][0][0], wgt, tx, ty, den);
    conv_pass5<CIN>(&s_d[0][0][0], wgt, tx, ty, nom);

    // epilogue: den <- cv, nom <- U'
    #pragma unroll
    for (int co = 0; co < 2; ++co) {
        float s = 0.f;
        for (int i = 0; i < CIN * 25; ++i) s += wgt[co * CIN * 25 + i];
        const float is = 1.0f / s;
        const float bb = bias[co];
        #pragma unroll
        for (int o = 0; o < 2; ++o)
            #pragma unroll
            for (int p = 0; p < 4; ++p) {
                const float xo = nom[co][o][p] * frcp(den[co][o][p] + EPSF) + bb;
                const float cv = den[co][o][p] * is;
                den[co][o][p] = cv;
                nom[co][o][p] = xo * cv;
            }
    }

    #pragma unroll
    for (int co = 0; co < 2; ++co)
        #pragma unroll
        for (int o = 0; o < 2; ++o) {
            const int a = ((b * 2 + co) << (2 * LOGHW - 2))
                        + ((bh + 2 * ty + o) << (LOGHW - 2)) + (bw >> 2) + tx;
            ((float4*)uout)[a] = make_float4(nom[co][o][0], nom[co][o][1], nom[co][o][2], nom[co][o][3]);
            ((float4*)cout)[a] = make_float4(den[co][o][0], den[co][o][1], den[co][o][2], den[co][o][3]);
        }

    if (POOL) {
        #pragma unroll
        for (int co = 0; co < 2; ++co) {
            float pg[2], pm[2];
            #pragma unroll
            for (int pc = 0; pc < 2; ++pc) {
                float m = den[co][0][2*pc],     g = nom[co][0][2*pc];
                if (den[co][0][2*pc+1] > m) { m = den[co][0][2*pc+1]; g = nom[co][0][2*pc+1]; }
                if (den[co][1][2*pc]   > m) { m = den[co][1][2*pc];   g = nom[co][1][2*pc]; }
                if (den[co][1][2*pc+1] > m) { m = den[co][1][2*pc+1]; g = nom[co][1][2*pc+1]; }
                pg[pc] = g * 0.25f;
                pm[pc] = m * 0.25f;
            }
            const int pa = ((b * 2 + co) << (2 * (LOGHW - 1)))
                         + (((bh >> 1) + ty) << (LOGHW - 1)) + (bw >> 1) + 2 * tx;
            *(float2*)&poolU[pa] = make_float2(pg[0], pg[1]);
            *(float2*)&poolC[pa] = make_float2(pm[0], pm[1]);
        }
    }
}

// ===========================================================================
// cat core: 2x4-blocked nconv over concat(skip @full, up2(low @half)), K=3.
// Tile 64x32. Skip tile stride 72 (18 f4 slots) -> 49.5 KB LDS, 3 blocks/CU.
// ===========================================================================
template<bool UP_FIRST, int LOGHW, bool FINAL>
__global__ __launch_bounds__(256, 3)
void cat_blk(const float* __restrict__ skU, const float* __restrict__ skC,
             const float* __restrict__ loU, const float* __restrict__ loC,
             const float* __restrict__ wgt, const float* __restrict__ bias,
             float* __restrict__ uout, float* __restrict__ cout,
             const float* __restrict__ w7, const float* __restrict__ b7)
{
    constexpr int HW = 1 << LOGHW;
    constexpr int HWL = HW >> 1;
    constexpr int SK0 = UP_FIRST ? 2 : 0;
    constexpr int LO0 = UP_FIRST ? 0 : 2;
    __shared__ __align__(16) float s_d[2][34][72],  s_c[2][34][72];
    __shared__ __align__(16) float lo_d[2][18][40], lo_c[2][18][40];

    const int tid = threadIdx.x;
    const int bw = blockIdx.x * 64;
    const int bh = blockIdx.y * 32;
    const int b  = blockIdx.z;

    const float4* sU4 = (const float4*)skU;
    const float4* sC4 = (const float4*)skC;
    for (int i = tid; i < 2 * 34 * 18; i += 256) {
        const int ci = i / (34 * 18);
        const int r  = (i / 18) % 34;
        const int k  = i % 18;
        const int gh = bh - 1 + r;
        const int gw4 = (bw >> 2) - 1 + k;
        float4 dd = make_float4(0.f, 0.f, 0.f, 0.f);
        float4 cc = make_float4(0.f, 0.f, 0.f, 0.f);
        if ((unsigned)gh < (unsigned)HW && (unsigned)gw4 < (unsigned)(HW >> 2)) {
            const int a = ((b * 2 + ci) << (2 * LOGHW - 2)) + (gh << (LOGHW - 2)) + gw4;
            dd = sU4[a];
            cc = sC4[a];
        }
        *(float4*)&s_d[ci][r][4 * k] = dd;
        *(float4*)&s_c[ci][r][4 * k] = cc;
    }
    const float4* lU4 = (const float4*)loU;
    const float4* lC4 = (const float4*)loC;
    for (int i = tid; i < 2 * 18 * 10; i += 256) {
        const int ci = i / 180;
        const int r  = (i / 10) % 18;
        const int k  = i % 10;
        const int gr = (bh >> 1) - 1 + r;
        const int gc4 = (bw >> 3) - 1 + k;
        float4 dd = make_float4(0.f, 0.f, 0.f, 0.f);
        float4 cc = make_float4(0.f, 0.f, 0.f, 0.f);
        if ((unsigned)gr < (unsigned)HWL && (unsigned)gc4 < (unsigned)(HWL >> 2)) {
            const int a = ((b * 2 + ci) << (2 * (LOGHW - 1) - 2)) + (gr << (LOGHW - 3)) + gc4;
            dd = lU4[a];
            cc = lC4[a];
        }
        *(float4*)&lo_d[ci][r][4 * k] = dd;
        *(float4*)&lo_c[ci][r][4 * k] = cc;
    }
    __syncthreads();

    const int tx = tid & 15;
    const int ty = tid >> 4;

    float den[2][2][4], nom[2][2][4];
    #pragma unroll
    for (int co = 0; co < 2; ++co)
        #pragma unroll
        for (int o = 0; o < 2; ++o)
            #pragma unroll
            for (int p = 0; p < 4; ++p) { den[co][o][p] = 0.f; nom[co][o][p] = 0.f; }

    // ---- skip channels (full res), K=3
    #pragma unroll
    for (int j = 0; j < 4; ++j) {
        const int lr = 2 * ty + j;
        #pragma unroll
        for (int ci = 0; ci < 2; ++ci) {
            float wd[12], wc[12];
            #pragma unroll
            for (int c = 0; c < 3; ++c) {
                const float4 t = *(const float4*)&s_d[ci][lr][4 * (tx + c)];
                wd[4*c] = t.x; wd[4*c+1] = t.y; wd[4*c+2] = t.z; wd[4*c+3] = t.w;
                const float4 u = *(const float4*)&s_c[ci][lr][4 * (tx + c)];
                wc[4*c] = u.x; wc[4*c+1] = u.y; wc[4*c+2] = u.z; wc[4*c+3] = u.w;
            }
            #pragma unroll
            for (int orow = 0; orow < 2; ++orow) {
                const int kh = j - orow;
                if (kh < 0 || kh > 2) continue;
                #pragma unroll
                for (int kw = 0; kw < 3; ++kw) {
                    const float w0 = wgt[((0 * 4 + SK0 + ci) * 3 + kh) * 3 + kw];
                    const float w1 = wgt[((1 * 4 + SK0 + ci) * 3 + kh) * 3 + kw];
                    #pragma unroll
                    for (int p = 0; p < 4; ++p) {
                        const int m = p + kw + 3;
                        den[0][orow][p] = fmaf(w0, wc[m], den[0][orow][p]);
                        nom[0][orow][p] = fmaf(w0, wd[m], nom[0][orow][p]);
                        den[1][orow][p] = fmaf(w1, wc[m], den[1][orow][p]);
                        nom[1][orow][p] = fmaf(w1, wd[m], nom[1][orow][p]);
                    }
                }
            }
        }
    }

    // ---- low channels (half res, replicated)
    #pragma unroll
    for (int jl = 0; jl < 3; ++jl) {
        const int lrow = ty + jl;
        #pragma unroll
        for (int ci = 0; ci < 2; ++ci) {
            float wld[6], wlc[6];
            #pragma unroll
            for (int i2 = 0; i2 < 3; ++i2) {
                const float2 t = *(const float2*)&lo_d[ci][lrow][2 * tx + 2 + 2 * i2];
                wld[2*i2] = t.x; wld[2*i2+1] = t.y;
                const float2 u = *(const float2*)&lo_c[ci][lrow][2 * tx + 2 + 2 * i2];
                wlc[2*i2] = u.x; wlc[2*i2+1] = u.y;
            }
            #pragma unroll
            for (int orow = 0; orow < 2; ++orow)
                #pragma unroll
                for (int khp = 0; khp < 3; ++khp) {
                    const int need_jl = (orow == 0) ? (khp == 0 ? 0 : 1)
                                                    : (khp == 2 ? 2 : 1);
                    if (need_jl != jl) continue;
                    #pragma unroll
                    for (int kwp = 0; kwp < 3; ++kwp) {
                        const float w0 = wgt[((0 * 4 + LO0 + ci) * 3 + khp) * 3 + kwp];
                        const float w1 = wgt[((1 * 4 + LO0 + ci) * 3 + khp) * 3 + kwp];
                        #pragma unroll
                        for (int p = 0; p < 4; ++p) {
                            const int t = p + kwp - 1;
                            const int m = ((t < 0) ? -1 : (t >> 1)) + 2;
                            den[0][orow][p] = fmaf(w0, wlc[m], den[0][orow][p]);
                            nom[0][orow][p] = fmaf(w0, wld[m], nom[0][orow][p]);
                            den[1][orow][p] = fmaf(w1, wlc[m], den[1][orow][p]);
                            nom[1][orow][p] = fmaf(w1, wld[m], nom[1][orow][p]);
                        }
                    }
                }
        }
    }

    // epilogue
    #pragma unroll
    for (int co = 0; co < 2; ++co) {
        float s = 0.f;
        for (int i = 0; i < 36; ++i) s += wgt[co * 36 + i];
        const float is = 1.0f / s;
        const float bb = bias[co];
        #pragma unroll
        for (int o = 0; o < 2; ++o)
            #pragma unroll
            for (int p = 0; p < 4; ++p) {
                const float xo = nom[co][o][p] * frcp(den[co][o][p] + EPSF) + bb;
                const float cv = den[co][o][p] * is;
                den[co][o][p] = cv;
                nom[co][o][p] = xo * cv;
            }
    }

    if (FINAL) {
        const float w70 = w7[0], w71 = w7[1], bb7 = b7[0];
        const float inv = frcp(w70 + w71);
        #pragma unroll
        for (int o = 0; o < 2; ++o) {
            float4 xo4, cc4;
            #pragma unroll
            for (int p = 0; p < 4; ++p) {
                const float d1 = w70 * den[0][o][p] + w71 * den[1][o][p];
                (&xo4.x)[p] = (w70 * nom[0][o][p] + w71 * nom[1][o][p]) * frcp(d1 + EPSF) + bb7;
                (&cc4.x)[p] = d1 * inv;
            }
            const int a = (b << (2 * LOGHW - 2)) + ((bh + 2 * ty + o) << (LOGHW - 2)) + (bw >> 2) + tx;
            ((float4*)uout)[a] = xo4;
            ((float4*)uout)[(1 << 19) + a] = cc4;
        }
    } else {
        #pragma unroll
        for (int co = 0; co < 2; ++co)
            #pragma unroll
            for (int o = 0; o < 2; ++o) {
                const int a = ((b * 2 + co) << (2 * LOGHW - 2))
                            + ((bh + 2 * ty + o) << (LOGHW - 2)) + (bw >> 2) + tx;
                ((float4*)uout)[a] = make_float4(nom[co][o][0], nom[co][o][1], nom[co][o][2], nom[co][o][3]);
                ((float4*)cout)[a] = make_float4(den[co][o][0], den[co][o][1], den[co][o][2], den[co][o][3]);
            }
    }
}

// ===========================================================================
// Small-res kernels (proven): conv_core/conv_low/nconv_tiled/cat_tiled
// ===========================================================================
template<int NCI, int CI0, int CINT, int K, int ROWS>
__device__ __forceinline__ void conv_core(const float* __restrict__ s_d,
                                          const float* __restrict__ s_c,
                                          const float* __restrict__ wgt,
                                          int lh, int lw,
                                          float den[2][4], float nom[2][4])
{
    constexpr int JOFF = 4 - (K / 2);
    #pragma unroll
    for (int kh = 0; kh < K; ++kh) {
        #pragma unroll
        for (int ci = 0; ci < NCI; ++ci) {
            const float4* rd = (const float4*)(s_d + (ci * ROWS + lh + kh) * 72 + lw);
            const float4* rc = (const float4*)(s_c + (ci * ROWS + lh + kh) * 72 + lw);
            float wd[12], wc[12];
            #pragma unroll
            for (int q = 0; q < 3; ++q) {
                const float4 t = rd[q];
                wd[4*q] = t.x; wd[4*q+1] = t.y; wd[4*q+2] = t.z; wd[4*q+3] = t.w;
                const float4 u = rc[q];
                wc[4*q] = u.x; wc[4*q+1] = u.y; wc[4*q+2] = u.z; wc[4*q+3] = u.w;
            }
            #pragma unroll
            for (int kw = 0; kw < K; ++kw) {
                const float w0 = wgt[((0 * CINT + CI0 + ci) * K + kh) * K + kw];
                const float w1 = wgt[((1 * CINT + CI0 + ci) * K + kh) * K + kw];
                #pragma unroll
                for (int p = 0; p < 4; ++p) {
                    const int j = p + kw + JOFF;
                    den[0][p] = fmaf(w0, wc[j], den[0][p]);
                    nom[0][p] = fmaf(w0, wd[j], nom[0][p]);
                    den[1][p] = fmaf(w1, wc[j], den[1][p]);
                    nom[1][p] = fmaf(w1, wd[j], nom[1][p]);
                }
            }
        }
    }
}

template<int LO0>
__device__ __forceinline__ void conv_low(const float* __restrict__ s_lo_d,
                                         const float* __restrict__ s_lo_c,
                                         const float* __restrict__ wgt,
                                         int lh, int lw,
                                         float den[2][4], float nom[2][4])
{
    #pragma unroll
    for (int kh = 0; kh < 3; ++kh) {
        const int rel_r = ((lh + kh - 1) >> 1) + 1;
        #pragma unroll
        for (int lci = 0; lci < 2; ++lci) {
            const float* rd = s_lo_d + (lci * 10 + rel_r) * 40 + (lw >> 1) + 2;
            const float* rc = s_lo_c + (lci * 10 + rel_r) * 40 + (lw >> 1) + 2;
            float wd[6], wc[6];
            #pragma unroll
            for (int q = 0; q < 3; ++q) {
                const float2 t = *(const float2*)(rd + 2 * q);
                wd[2*q] = t.x; wd[2*q+1] = t.y;
                const float2 u = *(const float2*)(rc + 2 * q);
                wc[2*q] = u.x; wc[2*q+1] = u.y;
            }
            #pragma unroll
            for (int kw = 0; kw < 3; ++kw) {
                const float w0 = wgt[((0 * 4 + LO0 + lci) * 3 + kh) * 3 + kw];
                const float w1 = wgt[((1 * 4 + LO0 + lci) * 3 + kh) * 3 + kw];
                #pragma unroll
                for (int p = 0; p < 4; ++p) {
                    const int t = p + kw - 1;
                    const int jl = ((t < 0) ? -1 : (t >> 1)) + 2;
                    den[0][p] = fmaf(w0, wc[jl], den[0][p]);
                    nom[0][p] = fmaf(w0, wd[jl], nom[0][p]);
                    den[1][p] = fmaf(w1, wc[jl], den[1][p]);
                    nom[1][p] = fmaf(w1, wd[jl], nom[1][p]);
                }
            }
        }
    }
}

template<int CINT, int K>
__device__ __forceinline__ void nconv_epilogue(const float* __restrict__ wgt,
                                               const float* __restrict__ bias,
                                               float den[2][4], float nom[2][4],
                                               float4 uo[2], float4 co4[2])
{
    #pragma unroll
    for (int c = 0; c < 2; ++c) {
        float s = 0.f;
        for (int i = 0; i < CINT * K * K; ++i) s += wgt[c * CINT * K * K + i];
        const float is = 1.0f / s;
        const float bb = bias[c];
        #pragma unroll
        for (int p = 0; p < 4; ++p) {
            const float xo = nom[c][p] * frcp(den[c][p] + EPSF) + bb;
            const float cv = den[c][p] * is;
            (&co4[c].x)[p] = cv;
            (&uo[c].x)[p]  = xo * cv;
        }
    }
}

template<int CIN, int K, int LOGHW, bool IN_IS_U, bool POOL>
__global__ __launch_bounds__(256)
void nconv_tiled(const float* __restrict__ xin, const float* __restrict__ cin_,
                 const float* __restrict__ wgt, const float* __restrict__ bias,
                 float* __restrict__ uout, float* __restrict__ cout,
                 float* __restrict__ poolU, float* __restrict__ poolC)
{
    constexpr int HW = 1 << LOGHW;
    constexpr int PAD = K / 2;
    constexpr int TH = 16;
    constexpr int ROWS = TH + 2 * PAD;
    constexpr int NC4 = 18;
    __shared__ __align__(16) float s_d[CIN][ROWS][72];
    __shared__ __align__(16) float s_c[CIN][ROWS][72];

    const int tid = threadIdx.x;
    const int base_w = blockIdx.x * 64;
    const int base_h = blockIdx.y * TH;
    const int b = blockIdx.z;

    constexpr int SLOTS = CIN * ROWS * NC4;
    const float4* x4 = (const float4*)xin;
    const float4* c4p = (const float4*)cin_;
    for (int i = tid; i < SLOTS; i += 256) {
        const int ci = i / (ROWS * NC4);
        const int r  = (i / NC4) % ROWS;
        const int cf = i % NC4;
        const int gh = base_h - PAD + r;
        const int gw4 = (base_w >> 2) + cf - 1;
        float4 dd = make_float4(0.f, 0.f, 0.f, 0.f);
        float4 cc = make_float4(0.f, 0.f, 0.f, 0.f);
        if ((unsigned)gh < (unsigned)HW && (unsigned)gw4 < (unsigned)(HW >> 2)) {
            const int a = ((b * CIN + ci) << (2 * LOGHW - 2)) + (gh << (LOGHW - 2)) + gw4;
            const float4 xx = x4[a];
            cc = c4p[a];
            if (IN_IS_U) dd = xx;
            else dd = make_float4(xx.x * cc.x, xx.y * cc.y, xx.z * cc.z, xx.w * cc.w);
        }
        *(float4*)&s_d[ci][r][cf * 4] = dd;
        *(float4*)&s_c[ci][r][cf * 4] = cc;
    }
    __syncthreads();

    const int lh = tid >> 4;
    const int lw = (tid & 15) << 2;
    float den[2][4], nom[2][4];
    #pragma unroll
    for (int c = 0; c < 2; ++c)
        #pragma unroll
        for (int p = 0; p < 4; ++p) { den[c][p] = 0.f; nom[c][p] = 0.f; }

    conv_core<CIN, 0, CIN, K, ROWS>(&s_d[0][0][0], &s_c[0][0][0], wgt, lh, lw, den, nom);

    float4 uo[2], co4[2];
    nconv_epilogue<CIN, K>(wgt, bias, den, nom, uo, co4);

    const int oh = base_h + lh;
    #pragma unroll
    for (int c = 0; c < 2; ++c) {
        const int a = ((b * 2 + c) << (2 * LOGHW - 2)) + (oh << (LOGHW - 2)) + ((base_w + lw) >> 2);
        ((float4*)uout)[a] = uo[c];
        ((float4*)cout)[a] = co4[c];
    }

    if (POOL) {
        __syncthreads();
        float* pu = &s_d[0][0][0];
        float* pcb = &s_c[0][0][0];
        #pragma unroll
        for (int c = 0; c < 2; ++c) {
            *(float4*)&pu[(c * 16 + lh) * 64 + lw] = uo[c];
            *(float4*)&pcb[(c * 16 + lh) * 64 + lw] = co4[c];
        }
        __syncthreads();
        #pragma unroll
        for (int rep = 0; rep < 2; ++rep) {
            const int o = tid + rep * 256;
            const int ch = o >> 8;
            const int idx = o & 255;
            const int pr = idx >> 5;
            const int pcc = idx & 31;
            const int bse = (ch * 16 + 2 * pr) * 64 + 2 * pcc;
            const float c00 = pcb[bse],      c01 = pcb[bse + 1];
            const float c10 = pcb[bse + 64], c11 = pcb[bse + 65];
            float m = c00; float g = pu[bse];
            if (c01 > m) { m = c01; g = pu[bse + 1]; }
            if (c10 > m) { m = c10; g = pu[bse + 64]; }
            if (c11 > m) { m = c11; g = pu[bse + 65]; }
            const int pa = ((b * 2 + ch) << (2 * (LOGHW - 1)))
                         + (((base_h >> 1) + pr) << (LOGHW - 1)) + (base_w >> 1) + pcc;
            poolU[pa] = g * 0.25f;
            poolC[pa] = m * 0.25f;
        }
    }
}

template<bool UP_FIRST, int LOGHW>
__global__ __launch_bounds__(256)
void nconv_cat_tiled(const float* __restrict__ skU, const float* __restrict__ skC,
                     const float* __restrict__ loU, const float* __restrict__ loC,
                     const float* __restrict__ wgt, const float* __restrict__ bias,
                     float* __restrict__ uout, float* __restrict__ cout)
{
    constexpr int HW = 1 << LOGHW;
    constexpr int HWL = HW >> 1;
    constexpr int TH = 16;
    constexpr int ROWS = TH + 2;
    constexpr int NC4 = 18;
    constexpr int SK0 = UP_FIRST ? 2 : 0;
    constexpr int LO0 = UP_FIRST ? 0 : 2;
    __shared__ __align__(16) float s_d[2][ROWS][72];
    __shared__ __align__(16) float s_c[2][ROWS][72];
    __shared__ __align__(16) float s_lo_d[2][10][40];
    __shared__ __align__(16) float s_lo_c[2][10][40];

    const int tid = threadIdx.x;
    const int base_w = blockIdx.x * 64;
    const int base_h = blockIdx.y * TH;
    const int b = blockIdx.z;

    constexpr int SLOTS = 2 * ROWS * NC4;
    const float4* sU4 = (const float4*)skU;
    const float4* sC4 = (const float4*)skC;
    for (int i = tid; i < SLOTS; i += 256) {
        const int ci = i / (ROWS * NC4);
        const int r  = (i / NC4) % ROWS;
        const int cf = i % NC4;
        const int gh = base_h - 1 + r;
        const int gw4 = (base_w >> 2) + cf - 1;
        float4 dd = make_float4(0.f, 0.f, 0.f, 0.f);
        float4 cc = make_float4(0.f, 0.f, 0.f, 0.f);
        if ((unsigned)gh < (unsigned)HW && (unsigned)gw4 < (unsigned)(HW >> 2)) {
            const int a = ((b * 2 + ci) << (2 * LOGHW - 2)) + (gh << (LOGHW - 2)) + gw4;
            dd = sU4[a];
            cc = sC4[a];
        }
        *(float4*)&s_d[ci][r][cf * 4] = dd;
        *(float4*)&s_c[ci][r][cf * 4] = cc;
    }
    constexpr int LO_SLOTS = 2 * 10 * 10;
    const int lo_r0 = (base_h >> 1) - 1;
    const int lo_c4_0 = (base_w >> 3) - 1;
    const float4* lU4 = (const float4*)loU;
    const float4* lC4 = (const float4*)loC;
    for (int i = tid; i < LO_SLOTS; i += 256) {
        const int ci = i / 100;
        const int r  = (i / 10) % 10;
        const int cf = i % 10;
        const int gr = lo_r0 + r;
        const int gc4 = lo_c4_0 + cf;
        float4 dd = make_float4(0.f, 0.f, 0.f, 0.f);
        float4 cc = make_float4(0.f, 0.f, 0.f, 0.f);
        if ((unsigned)gr < (unsigned)HWL && (unsigned)gc4 < (unsigned)(HWL >> 2)) {
            const int a = ((b * 2 + ci) << (2 * (LOGHW - 1) - 2)) + (gr << (LOGHW - 3)) + gc4;
            dd = lU4[a];
            cc = lC4[a];
        }
        *(float4*)&s_lo_d[ci][r][cf * 4] = dd;
        *(float4*)&s_lo_c[ci][r][cf * 4] = cc;
    }
    __syncthreads();

    const int lh = tid >> 4;
    const int lw = (tid & 15) << 2;
    float den[2][4], nom[2][4];
    #pragma unroll
    for (int c = 0; c < 2; ++c)
        #pragma unroll
        for (int p = 0; p < 4; ++p) { den[c][p] = 0.f; nom[c][p] = 0.f; }

    conv_core<2, SK0, 4, 3, ROWS>(&s_d[0][0][0], &s_c[0][0][0], wgt, lh, lw, den, nom);
    conv_low<LO0>(&s_lo_d[0][0][0], &s_lo_c[0][0][0], wgt, lh, lw, den, nom);

    float4 uo[2], co4[2];
    nconv_epilogue<4, 3>(wgt, bias, den, nom, uo, co4);

    const int oh = base_h + lh;
    #pragma unroll
    for (int c = 0; c < 2; ++c) {
        const int a = ((b * 2 + c) << (2 * LOGHW - 2)) + (oh << (LOGHW - 2)) + ((base_w + lw) >> 2);
        ((float4*)uout)[a] = uo[c];
        ((float4*)cout)[a] = co4[c];
    }
}

// ---------------------------------------------------------------------------
extern "C" void kernel_launch(void* const* d_in, const int* in_sizes, int n_in,
                              void* d_out, int out_size, void* d_ws, size_t ws_size,
                              hipStream_t stream) {
    (void)in_sizes; (void)n_in; (void)out_size; (void)ws_size;
    const float* x0 = (const float*)d_in[0];
    const float* c0 = (const float*)d_in[1];
    const float* w1 = (const float*)d_in[2];  const float* b1 = (const float*)d_in[3];
    const float* w2 = (const float*)d_in[4];  const float* b2 = (const float*)d_in[5];
    const float* w3 = (const float*)d_in[6];  const float* b3 = (const float*)d_in[7];
    const float* w4 = (const float*)d_in[8];  const float* b4 = (const float*)d_in[9];
    const float* w5 = (const float*)d_in[10]; const float* b5 = (const float*)d_in[11];
    const float* w6 = (const float*)d_in[12]; const float* b6 = (const float*)d_in[13];
    const float* w7 = (const float*)d_in[14]; const float* b7 = (const float*)d_in[15];

    float* ws = (float*)d_ws;
    const size_t S512 = 8ull * 2 * 512 * 512;
    const size_t S256 = 8ull * 2 * 256 * 256;
    const size_t S128 = 8ull * 2 * 128 * 128;
    const size_t S64  = 8ull * 2 * 64  * 64;

    float* X1x = ws;            float* X1c = ws + S512;
    float* Ax  = ws + 2 * S512; float* Ac  = ws + 3 * S512;
    float* Bx  = ws + 4 * S512; float* Bc  = ws + 5 * S512;
    float* x23x = Ax;               float* x23c = Ax + S256;
    float* x2x  = Ax + 2 * S256;    float* x2c  = Ax + 3 * S256;
    float* p1x  = Ax + 4 * S256;    float* p1c  = Ax + 5 * S256;
    float* qx   = Ax + 6 * S256;    float* qc   = Ax + 7 * S256;
    float* x3x  = Bx;               float* x3c  = Bx + S128;
    float* p2x  = Bx + 2 * S128;    float* p2c  = Bx + 3 * S128;
    float* x34x = Bx + 4 * S128;    float* x34c = Bx + 5 * S128;
    float* p3x  = Bx + 6 * S128;            float* p3c = Bx + 6 * S128 + S64;
    float* x4x  = Bx + 6 * S128 + 2 * S64;  float* x4c = Bx + 6 * S128 + 3 * S64;

    // Encoder @512 (pipelined split-pass core)
    nconv_rb<1, 9, false, false><<<dim3(8, 16, 8), 256, 0, stream>>>(
        x0, c0, w1, b1, Ax, Ac, nullptr, nullptr);
    nconv_rb<2, 9, true, false><<<dim3(8, 16, 8), 256, 0, stream>>>(
        Ax, Ac, w2, b2, Bx, Bc, nullptr, nullptr);
    nconv_rb<2, 9, true, true><<<dim3(8, 16, 8), 256, 0, stream>>>(
        Bx, Bc, w3, b3, X1x, X1c, p1x, p1c);
    // @256
    nconv_rb<2, 8, true, false><<<dim3(4, 8, 8), 256, 0, stream>>>(
        p1x, p1c, w2, b2, qx, qc, nullptr, nullptr);
    nconv_rb<2, 8, true, true><<<dim3(4, 8, 8), 256, 0, stream>>>(
        qx, qc, w3, b3, x2x, x2c, p2x, p2c);
    // @128 + pool, @64 (old core)
    nconv_tiled<2, 5, 7, true, true><<<dim3(2, 8, 8), 256, 0, stream>>>(
        p2x, p2c, w2, b2, x3x, x3c, p3x, p3c);
    nconv_tiled<2, 5, 6, true, false><<<dim3(1, 4, 8), 256, 0, stream>>>(
        p3x, p3c, w2, b2, x4x, x4c, nullptr, nullptr);
    // Decoder
    nconv_cat_tiled<false, 7><<<dim3(2, 8, 8), 256, 0, stream>>>(
        x3x, x3c, x4x, x4c, w4, b4, x34x, x34c);
    cat_blk<false, 8, false><<<dim3(4, 8, 8), 256, 0, stream>>>(
        x2x, x2c, x34x, x34c, w5, b5, x23x, x23c, nullptr, nullptr);
    cat_blk<true, 9, true><<<dim3(8, 16, 8), 256, 0, stream>>>(
        X1x, X1c, x23x, x23c, w6, b6, (float*)d_out, nullptr, w7, b7);
}

// Round 7
// 140.995 us; speedup vs baseline: 1.2526x; 1.0680x over previous
//
#include <hip/hip_runtime.h>

#define EPSF 1e-20f

__device__ __forceinline__ float frcp(float x) { return __builtin_amdgcn_rcpf(x); }

// ===========================================================================
// Pipeline in (U, c) representation, U = x*c.
//   nconv: den = conv(c); nom = conv(U); x = nom/(den+eps)+b; c' = den/sum(w);
//          U' = x*c'.
//   maxpool (argmax over c, torch first-max): U' = U_sel/4, c' = c_max/4.
//   up2: replicate (fused as half-res reads).
//   final 1x1: out = (w0*U0+w1*U1)/(w0*c0+w1*c1+eps)+b ; cout = den/(w0+w1).
// ===========================================================================

// ---------------------------------------------------------------------------
// Conv core on LDS tiles, row stride 72, window 12 floats at lw.
// ---------------------------------------------------------------------------
template<int NCI, int CI0, int CINT, int K, int ROWS>
__device__ __forceinline__ void conv_core(const float* __restrict__ s_d,
                                          const float* __restrict__ s_c,
                                          const float* __restrict__ wgt,
                                          int lh, int lw,
                                          float den[2][4], float nom[2][4])
{
    constexpr int JOFF = 4 - (K / 2);
    #pragma unroll
    for (int kh = 0; kh < K; ++kh) {
        #pragma unroll
        for (int ci = 0; ci < NCI; ++ci) {
            const float4* rd = (const float4*)(s_d + (ci * ROWS + lh + kh) * 72 + lw);
            const float4* rc = (const float4*)(s_c + (ci * ROWS + lh + kh) * 72 + lw);
            float wd[12], wc[12];
            #pragma unroll
            for (int q = 0; q < 3; ++q) {
                const float4 t = rd[q];
                wd[4*q] = t.x; wd[4*q+1] = t.y; wd[4*q+2] = t.z; wd[4*q+3] = t.w;
                const float4 u = rc[q];
                wc[4*q] = u.x; wc[4*q+1] = u.y; wc[4*q+2] = u.z; wc[4*q+3] = u.w;
            }
            #pragma unroll
            for (int kw = 0; kw < K; ++kw) {
                const float w0 = wgt[((0 * CINT + CI0 + ci) * K + kh) * K + kw];
                const float w1 = wgt[((1 * CINT + CI0 + ci) * K + kh) * K + kw];
                #pragma unroll
                for (int p = 0; p < 4; ++p) {
                    const int j = p + kw + JOFF;
                    den[0][p] = fmaf(w0, wc[j], den[0][p]);
                    nom[0][p] = fmaf(w0, wd[j], nom[0][p]);
                    den[1][p] = fmaf(w1, wc[j], den[1][p]);
                    nom[1][p] = fmaf(w1, wd[j], nom[1][p]);
                }
            }
        }
    }
}

template<int LO0>
__device__ __forceinline__ void conv_low(const float* __restrict__ s_lo_d,
                                         const float* __restrict__ s_lo_c,
                                         const float* __restrict__ wgt,
                                         int lh, int lw,
                                         float den[2][4], float nom[2][4])
{
    #pragma unroll
    for (int kh = 0; kh < 3; ++kh) {
        const int rel_r = ((lh + kh - 1) >> 1) + 1;
        #pragma unroll
        for (int lci = 0; lci < 2; ++lci) {
            const float* rd = s_lo_d + (lci * 10 + rel_r) * 40 + (lw >> 1) + 2;
            const float* rc = s_lo_c + (lci * 10 + rel_r) * 40 + (lw >> 1) + 2;
            float wd[6], wc[6];
            #pragma unroll
            for (int q = 0; q < 3; ++q) {
                const float2 t = *(const float2*)(rd + 2 * q);
                wd[2*q] = t.x; wd[2*q+1] = t.y;
                const float2 u = *(const float2*)(rc + 2 * q);
                wc[2*q] = u.x; wc[2*q+1] = u.y;
            }
            #pragma unroll
            for (int kw = 0; kw < 3; ++kw) {
                const float w0 = wgt[((0 * 4 + LO0 + lci) * 3 + kh) * 3 + kw];
                const float w1 = wgt[((1 * 4 + LO0 + lci) * 3 + kh) * 3 + kw];
                #pragma unroll
                for (int p = 0; p < 4; ++p) {
                    const int t = p + kw - 1;
                    const int jl = ((t < 0) ? -1 : (t >> 1)) + 2;
                    den[0][p] = fmaf(w0, wc[jl], den[0][p]);
                    nom[0][p] = fmaf(w0, wd[jl], nom[0][p]);
                    den[1][p] = fmaf(w1, wc[jl], den[1][p]);
                    nom[1][p] = fmaf(w1, wd[jl], nom[1][p]);
                }
            }
        }
    }
}

template<int CINT, int K>
__device__ __forceinline__ void nconv_epilogue(const float* __restrict__ wgt,
                                               const float* __restrict__ bias,
                                               float den[2][4], float nom[2][4],
                                               float4 uo[2], float4 co4[2])
{
    #pragma unroll
    for (int c = 0; c < 2; ++c) {
        float s = 0.f;
        for (int i = 0; i < CINT * K * K; ++i) s += wgt[c * CINT * K * K + i];
        const float is = 1.0f / s;
        const float bb = bias[c];
        #pragma unroll
        for (int p = 0; p < 4; ++p) {
            const float xo = nom[c][p] * frcp(den[c][p] + EPSF) + bb;
            const float cv = den[c][p] * is;
            (&co4[c].x)[p] = cv;
            (&uo[c].x)[p]  = xo * cv;
        }
    }
}

// ===========================================================================
// NEW: fused enc1(CIN=1, 5x5) + enc2(CIN=2, 5x5) @512. Tile 64x16.
// Stage A computes the 20x72 intermediate region into LDS with the
// conflict-free 16x16 mapping (two passes); stage B = proven conv_core.
// LDS 39.2 KB -> 4 blocks/CU.
// ===========================================================================
__device__ __forceinline__ void stageA_item(
    const float (*in_d)[84], const float (*in_c)[84],
    const float* __restrict__ wA, const float* __restrict__ bA,
    float isA0, float isA1, int r, int g, int bh, int bw,
    float (*mid_d)[20][72], float (*mid_c)[20][72])
{
    float den[2][4], nom[2][4];
    #pragma unroll
    for (int c = 0; c < 2; ++c)
        #pragma unroll
        for (int p = 0; p < 4; ++p) { den[c][p] = 0.f; nom[c][p] = 0.f; }

    #pragma unroll
    for (int kh = 0; kh < 5; ++kh) {
        const float* rd = &in_d[r + kh][4 * g];
        const float* rc = &in_c[r + kh][4 * g];
        float wd[12], wc[12];
        #pragma unroll
        for (int q = 0; q < 3; ++q) {
            const float4 t = *(const float4*)(rd + 4 * q);
            wd[4*q] = t.x; wd[4*q+1] = t.y; wd[4*q+2] = t.z; wd[4*q+3] = t.w;
            const float4 u = *(const float4*)(rc + 4 * q);
            wc[4*q] = u.x; wc[4*q+1] = u.y; wc[4*q+2] = u.z; wc[4*q+3] = u.w;
        }
        #pragma unroll
        for (int kw = 0; kw < 5; ++kw) {
            const float w0 = wA[(0 * 5 + kh) * 5 + kw];
            const float w1 = wA[(1 * 5 + kh) * 5 + kw + 20];   // 25 + kh*5+kw - 5... see below
            #pragma unroll
            for (int p = 0; p < 4; ++p) {
                const int m = p + kw + 2;
                den[0][p] = fmaf(w0, wc[m], den[0][p]);
                nom[0][p] = fmaf(w0, wd[m], nom[0][p]);
                den[1][p] = fmaf(w1, wc[m], den[1][p]);
                nom[1][p] = fmaf(w1, wd[m], nom[1][p]);
            }
        }
    }
    // NOTE on w1 index above: wA layout is [2][1][5][5]; channel1 base = 25.
    // (0*5+kh)*5+kw + 20 == 25 + (kh-1)*5 + kw  -> WRONG unless kh>=1.
    // Correct both explicitly here instead:
    // (we recompute channel-1 accumulators properly below if needed)

    const int orow = bh + r - 2;
    const bool rok = (unsigned)orow < 512u;
    float4 du[2], dc[2];
    #pragma unroll
    for (int c = 0; c < 2; ++c) {
        const float is = (c == 0) ? isA0 : isA1;
        const float bb = bA[c];
        #pragma unroll
        for (int p = 0; p < 4; ++p) {
            const int ocol = bw + 4 * g - 4 + p;
            const bool ok = rok && (unsigned)ocol < 512u;
            const float xo = nom[c][p] * frcp(den[c][p] + EPSF) + bb;
            const float cv = den[c][p] * is;
            (&dc[c].x)[p] = ok ? cv : 0.f;
            (&du[c].x)[p] = ok ? xo * cv : 0.f;
        }
        *(float4*)&mid_d[c][r][4 * g] = du[c];
        *(float4*)&mid_c[c][r][4 * g] = dc[c];
    }
}

__global__ __launch_bounds__(256)
void enc12_fused(const float* __restrict__ x0, const float* __restrict__ c0,
                 const float* __restrict__ wA, const float* __restrict__ bA,
                 const float* __restrict__ wB, const float* __restrict__ bB,
                 float* __restrict__ uout, float* __restrict__ cout)
{
    __shared__ __align__(16) float in_d[24][84], in_c[24][84];
    __shared__ __align__(16) float mid_d[2][20][72], mid_c[2][20][72];

    const int tid = threadIdx.x;
    const int bw = blockIdx.x * 64;
    const int bh = blockIdx.y * 16;
    const int b  = blockIdx.z;

    // Stage input: rows [bh-4, bh+20), cols [bw-8, bw+72)
    const float4* x4 = (const float4*)x0;
    const float4* c4 = (const float4*)c0;
    for (int i = tid; i < 480; i += 256) {
        const int r = i / 20, k = i % 20;
        const int gh = bh - 4 + r;
        const int gw4 = (bw >> 2) - 2 + k;
        float4 xx = make_float4(0.f, 0.f, 0.f, 0.f);
        float4 cc = make_float4(0.f, 0.f, 0.f, 0.f);
        if ((unsigned)gh < 512u && (unsigned)gw4 < 128u) {
            const int a = (b << 16) + (gh << 7) + gw4;
            xx = x4[a];
            cc = c4[a];
        }
        *(float4*)&in_d[r][4 * k] = make_float4(xx.x * cc.x, xx.y * cc.y, xx.z * cc.z, xx.w * cc.w);
        *(float4*)&in_c[r][4 * k] = cc;
    }

    float isA0, isA1;
    {
        float s0 = 0.f, s1 = 0.f;
        for (int i = 0; i < 25; ++i) { s0 += wA[i]; s1 += wA[25 + i]; }
        isA0 = 1.0f / s0;
        isA1 = 1.0f / s1;
    }
    __syncthreads();

    // Stage A over 20 rows x 18 f4-groups = 360 items, conflict-free mapping.
    {
        // fix the weight indexing: define a small lambda-free explicit item
        // computing with correct wA bases (0 and 25).
        // Pass A1: 256 items.
        {
            const int r = tid >> 4, g = tid & 15;
            // inline (correct) stage-A computation:
            float den[2][4], nom[2][4];
            #pragma unroll
            for (int c = 0; c < 2; ++c)
                #pragma unroll
                for (int p = 0; p < 4; ++p) { den[c][p] = 0.f; nom[c][p] = 0.f; }
            #pragma unroll
            for (int kh = 0; kh < 5; ++kh) {
                const float* rd = &in_d[r + kh][4 * g];
                const float* rc = &in_c[r + kh][4 * g];
                float wd[12], wc[12];
                #pragma unroll
                for (int q = 0; q < 3; ++q) {
                    const float4 t = *(const float4*)(rd + 4 * q);
                    wd[4*q] = t.x; wd[4*q+1] = t.y; wd[4*q+2] = t.z; wd[4*q+3] = t.w;
                    const float4 u = *(const float4*)(rc + 4 * q);
                    wc[4*q] = u.x; wc[4*q+1] = u.y; wc[4*q+2] = u.z; wc[4*q+3] = u.w;
                }
                #pragma unroll
                for (int kw = 0; kw < 5; ++kw) {
                    const float w0 = wA[kh * 5 + kw];
                    const float w1 = wA[25 + kh * 5 + kw];
                    #pragma unroll
                    for (int p = 0; p < 4; ++p) {
                        const int m = p + kw + 2;
                        den[0][p] = fmaf(w0, wc[m], den[0][p]);
                        nom[0][p] = fmaf(w0, wd[m], nom[0][p]);
                        den[1][p] = fmaf(w1, wc[m], den[1][p]);
                        nom[1][p] = fmaf(w1, wd[m], nom[1][p]);
                    }
                }
            }
            const int orow = bh + r - 2;
            const bool rok = (unsigned)orow < 512u;
            #pragma unroll
            for (int c = 0; c < 2; ++c) {
                const float is = (c == 0) ? isA0 : isA1;
                float4 du, dc;
                #pragma unroll
                for (int p = 0; p < 4; ++p) {
                    const int ocol = bw + 4 * g - 4 + p;
                    const bool ok = rok && (unsigned)ocol < 512u;
                    const float xo = nom[c][p] * frcp(den[c][p] + EPSF) + bA[c];
                    const float cv = den[c][p] * is;
                    (&dc.x)[p] = ok ? cv : 0.f;
                    (&du.x)[p] = ok ? xo * cv : 0.f;
                }
                *(float4*)&mid_d[c][r][4 * g] = du;
                *(float4*)&mid_c[c][r][4 * g] = dc;
            }
        }
        // Pass A2: remaining 104 items.
        if (tid < 104) {
            int r, g;
            if (tid < 64) { r = 16 + (tid >> 4); g = tid & 15; }
            else { const int t = tid - 64; r = t >> 1; g = 16 + (t & 1); }
            float den[2][4], nom[2][4];
            #pragma unroll
            for (int c = 0; c < 2; ++c)
                #pragma unroll
                for (int p = 0; p < 4; ++p) { den[c][p] = 0.f; nom[c][p] = 0.f; }
            #pragma unroll
            for (int kh = 0; kh < 5; ++kh) {
                const float* rd = &in_d[r + kh][4 * g];
                const float* rc = &in_c[r + kh][4 * g];
                float wd[12], wc[12];
                #pragma unroll
                for (int q = 0; q < 3; ++q) {
                    const float4 t = *(const float4*)(rd + 4 * q);
                    wd[4*q] = t.x; wd[4*q+1] = t.y; wd[4*q+2] = t.z; wd[4*q+3] = t.w;
                    const float4 u = *(const float4*)(rc + 4 * q);
                    wc[4*q] = u.x; wc[4*q+1] = u.y; wc[4*q+2] = u.z; wc[4*q+3] = u.w;
                }
                #pragma unroll
                for (int kw = 0; kw < 5; ++kw) {
                    const float w0 = wA[kh * 5 + kw];
                    const float w1 = wA[25 + kh * 5 + kw];
                    #pragma unroll
                    for (int p = 0; p < 4; ++p) {
                        const int m = p + kw + 2;
                        den[0][p] = fmaf(w0, wc[m], den[0][p]);
                        nom[0][p] = fmaf(w0, wd[m], nom[0][p]);
                        den[1][p] = fmaf(w1, wc[m], den[1][p]);
                        nom[1][p] = fmaf(w1, wd[m], nom[1][p]);
                    }
                }
            }
            const int orow = bh + r - 2;
            const bool rok = (unsigned)orow < 512u;
            #pragma unroll
            for (int c = 0; c < 2; ++c) {
                const float is = (c == 0) ? isA0 : isA1;
                float4 du, dc;
                #pragma unroll
                for (int p = 0; p < 4; ++p) {
                    const int ocol = bw + 4 * g - 4 + p;
                    const bool ok = rok && (unsigned)ocol < 512u;
                    const float xo = nom[c][p] * frcp(den[c][p] + EPSF) + bA[c];
                    const float cv = den[c][p] * is;
                    (&dc.x)[p] = ok ? cv : 0.f;
                    (&du.x)[p] = ok ? xo * cv : 0.f;
                }
                *(float4*)&mid_d[c][r][4 * g] = du;
                *(float4*)&mid_c[c][r][4 * g] = dc;
            }
        }
    }
    __syncthreads();

    // Stage B (enc2, CIN=2) with the proven core.
    const int lh = tid >> 4;
    const int lw = (tid & 15) << 2;
    float den[2][4], nom[2][4];
    #pragma unroll
    for (int c = 0; c < 2; ++c)
        #pragma unroll
        for (int p = 0; p < 4; ++p) { den[c][p] = 0.f; nom[c][p] = 0.f; }

    conv_core<2, 0, 2, 5, 20>(&mid_d[0][0][0], &mid_c[0][0][0], wB, lh, lw, den, nom);

    float4 uo[2], co4[2];
    nconv_epilogue<2, 5>(wB, bB, den, nom, uo, co4);

    const int oh = bh + lh;
    #pragma unroll
    for (int c = 0; c < 2; ++c) {
        const int a = ((b * 2 + c) << 16) + (oh << 7) + ((bw + lw) >> 2);
        ((float4*)uout)[a] = uo[c];
        ((float4*)cout)[a] = co4[c];
    }
}

// ===========================================================================
// Proven round-3 kernels.
// ===========================================================================
template<int CIN, int K, int LOGHW, bool IN_IS_U, bool POOL>
__global__ __launch_bounds__(256)
void nconv_tiled(const float* __restrict__ xin, const float* __restrict__ cin_,
                 const float* __restrict__ wgt, const float* __restrict__ bias,
                 float* __restrict__ uout, float* __restrict__ cout,
                 float* __restrict__ poolU, float* __restrict__ poolC)
{
    constexpr int HW = 1 << LOGHW;
    constexpr int PAD = K / 2;
    constexpr int TH = 16;
    constexpr int ROWS = TH + 2 * PAD;
    constexpr int NC4 = 18;
    __shared__ __align__(16) float s_d[CIN][ROWS][72];
    __shared__ __align__(16) float s_c[CIN][ROWS][72];

    const int tid = threadIdx.x;
    const int base_w = blockIdx.x * 64;
    const int base_h = blockIdx.y * TH;
    const int b = blockIdx.z;

    constexpr int SLOTS = CIN * ROWS * NC4;
    const float4* x4 = (const float4*)xin;
    const float4* c4p = (const float4*)cin_;
    for (int i = tid; i < SLOTS; i += 256) {
        const int ci = i / (ROWS * NC4);
        const int r  = (i / NC4) % ROWS;
        const int cf = i % NC4;
        const int gh = base_h - PAD + r;
        const int gw4 = (base_w >> 2) + cf - 1;
        float4 dd = make_float4(0.f, 0.f, 0.f, 0.f);
        float4 cc = make_float4(0.f, 0.f, 0.f, 0.f);
        if ((unsigned)gh < (unsigned)HW && (unsigned)gw4 < (unsigned)(HW >> 2)) {
            const int a = ((b * CIN + ci) << (2 * LOGHW - 2)) + (gh << (LOGHW - 2)) + gw4;
            const float4 xx = x4[a];
            cc = c4p[a];
            if (IN_IS_U) dd = xx;
            else dd = make_float4(xx.x * cc.x, xx.y * cc.y, xx.z * cc.z, xx.w * cc.w);
        }
        *(float4*)&s_d[ci][r][cf * 4] = dd;
        *(float4*)&s_c[ci][r][cf * 4] = cc;
    }
    __syncthreads();

    const int lh = tid >> 4;
    const int lw = (tid & 15) << 2;
    float den[2][4], nom[2][4];
    #pragma unroll
    for (int c = 0; c < 2; ++c)
        #pragma unroll
        for (int p = 0; p < 4; ++p) { den[c][p] = 0.f; nom[c][p] = 0.f; }

    conv_core<CIN, 0, CIN, K, ROWS>(&s_d[0][0][0], &s_c[0][0][0], wgt, lh, lw, den, nom);

    float4 uo[2], co4[2];
    nconv_epilogue<CIN, K>(wgt, bias, den, nom, uo, co4);

    const int oh = base_h + lh;
    #pragma unroll
    for (int c = 0; c < 2; ++c) {
        const int a = ((b * 2 + c) << (2 * LOGHW - 2)) + (oh << (LOGHW - 2)) + ((base_w + lw) >> 2);
        ((float4*)uout)[a] = uo[c];
        ((float4*)cout)[a] = co4[c];
    }

    if (POOL) {
        __syncthreads();
        float* pu = &s_d[0][0][0];
        float* pcb = &s_c[0][0][0];
        #pragma unroll
        for (int c = 0; c < 2; ++c) {
            *(float4*)&pu[(c * 16 + lh) * 64 + lw] = uo[c];
            *(float4*)&pcb[(c * 16 + lh) * 64 + lw] = co4[c];
        }
        __syncthreads();
        #pragma unroll
        for (int rep = 0; rep < 2; ++rep) {
            const int o = tid + rep * 256;
            const int ch = o >> 8;
            const int idx = o & 255;
            const int pr = idx >> 5;
            const int pcc = idx & 31;
            const int bse = (ch * 16 + 2 * pr) * 64 + 2 * pcc;
            const float c00 = pcb[bse],      c01 = pcb[bse + 1];
            const float c10 = pcb[bse + 64], c11 = pcb[bse + 65];
            float m = c00; float g = pu[bse];
            if (c01 > m) { m = c01; g = pu[bse + 1]; }
            if (c10 > m) { m = c10; g = pu[bse + 64]; }
            if (c11 > m) { m = c11; g = pu[bse + 65]; }
            const int pa = ((b * 2 + ch) << (2 * (LOGHW - 1)))
                         + (((base_h >> 1) + pr) << (LOGHW - 1)) + (base_w >> 1) + pcc;
            poolU[pa] = g * 0.25f;
            poolC[pa] = m * 0.25f;
        }
    }
}

template<bool UP_FIRST, int LOGHW, bool FINAL>
__global__ __launch_bounds__(256)
void nconv_cat_tiled(const float* __restrict__ skU, const float* __restrict__ skC,
                     const float* __restrict__ loU, const float* __restrict__ loC,
                     const float* __restrict__ wgt, const float* __restrict__ bias,
                     float* __restrict__ uout, float* __restrict__ cout,
                     const float* __restrict__ w7, const float* __restrict__ b7)
{
    constexpr int HW = 1 << LOGHW;
    constexpr int HWL = HW >> 1;
    constexpr int TH = 16;
    constexpr int ROWS = TH + 2;
    constexpr int NC4 = 18;
    constexpr int SK0 = UP_FIRST ? 2 : 0;
    constexpr int LO0 = UP_FIRST ? 0 : 2;
    __shared__ __align__(16) float s_d[2][ROWS][72];
    __shared__ __align__(16) float s_c[2][ROWS][72];
    __shared__ __align__(16) float s_lo_d[2][10][40];
    __shared__ __align__(16) float s_lo_c[2][10][40];

    const int tid = threadIdx.x;
    const int base_w = blockIdx.x * 64;
    const int base_h = blockIdx.y * TH;
    const int b = blockIdx.z;

    constexpr int SLOTS = 2 * ROWS * NC4;
    const float4* sU4 = (const float4*)skU;
    const float4* sC4 = (const float4*)skC;
    for (int i = tid; i < SLOTS; i += 256) {
        const int ci = i / (ROWS * NC4);
        const int r  = (i / NC4) % ROWS;
        const int cf = i % NC4;
        const int gh = base_h - 1 + r;
        const int gw4 = (base_w >> 2) + cf - 1;
        float4 dd = make_float4(0.f, 0.f, 0.f, 0.f);
        float4 cc = make_float4(0.f, 0.f, 0.f, 0.f);
        if ((unsigned)gh < (unsigned)HW && (unsigned)gw4 < (unsigned)(HW >> 2)) {
            const int a = ((b * 2 + ci) << (2 * LOGHW - 2)) + (gh << (LOGHW - 2)) + gw4;
            dd = sU4[a];
            cc = sC4[a];
        }
        *(float4*)&s_d[ci][r][cf * 4] = dd;
        *(float4*)&s_c[ci][r][cf * 4] = cc;
    }
    constexpr int LO_SLOTS = 2 * 10 * 10;
    const int lo_r0 = (base_h >> 1) - 1;
    const int lo_c4_0 = (base_w >> 3) - 1;
    const float4* lU4 = (const float4*)loU;
    const float4* lC4 = (const float4*)loC;
    for (int i = tid; i < LO_SLOTS; i += 256) {
        const int ci = i / 100;
        const int r  = (i / 10) % 10;
        const int cf = i % 10;
        const int gr = lo_r0 + r;
        const int gc4 = lo_c4_0 + cf;
        float4 dd = make_float4(0.f, 0.f, 0.f, 0.f);
        float4 cc = make_float4(0.f, 0.f, 0.f, 0.f);
        if ((unsigned)gr < (unsigned)HWL && (unsigned)gc4 < (unsigned)(HWL >> 2)) {
            const int a = ((b * 2 + ci) << (2 * (LOGHW - 1) - 2)) + (gr << (LOGHW - 3)) + gc4;
            dd = lU4[a];
            cc = lC4[a];
        }
        *(float4*)&s_lo_d[ci][r][cf * 4] = dd;
        *(float4*)&s_lo_c[ci][r][cf * 4] = cc;
    }
    __syncthreads();

    const int lh = tid >> 4;
    const int lw = (tid & 15) << 2;
    float den[2][4], nom[2][4];
    #pragma unroll
    for (int c = 0; c < 2; ++c)
        #pragma unroll
        for (int p = 0; p < 4; ++p) { den[c][p] = 0.f; nom[c][p] = 0.f; }

    conv_core<2, SK0, 4, 3, ROWS>(&s_d[0][0][0], &s_c[0][0][0], wgt, lh, lw, den, nom);
    conv_low<LO0>(&s_lo_d[0][0][0], &s_lo_c[0][0][0], wgt, lh, lw, den, nom);

    float4 uo[2], co4[2];
    nconv_epilogue<4, 3>(wgt, bias, den, nom, uo, co4);

    const int oh = base_h + lh;
    if (FINAL) {
        const float w70 = w7[0], w71 = w7[1], bb7 = b7[0];
        const float inv = frcp(w70 + w71);
        float4 xo4, cc4;
        #pragma unroll
        for (int p = 0; p < 4; ++p) {
            const float d1 = w70 * (&co4[0].x)[p] + w71 * (&co4[1].x)[p];
            (&xo4.x)[p] = (w70 * (&uo[0].x)[p] + w71 * (&uo[1].x)[p]) * frcp(d1 + EPSF) + bb7;
            (&cc4.x)[p] = d1 * inv;
        }
        const int a = (b << (2 * LOGHW - 2)) + (oh << (LOGHW - 2)) + ((base_w + lw) >> 2);
        ((float4*)uout)[a] = xo4;
        ((float4*)uout)[(1 << 19) + a] = cc4;
    } else {
        #pragma unroll
        for (int c = 0; c < 2; ++c) {
            const int a = ((b * 2 + c) << (2 * LOGHW - 2)) + (oh << (LOGHW - 2)) + ((base_w + lw) >> 2);
            ((float4*)uout)[a] = uo[c];
            ((float4*)cout)[a] = co4[c];
        }
    }
}

// ---------------------------------------------------------------------------
extern "C" void kernel_launch(void* const* d_in, const int* in_sizes, int n_in,
                              void* d_out, int out_size, void* d_ws, size_t ws_size,
                              hipStream_t stream) {
    (void)in_sizes; (void)n_in; (void)out_size; (void)ws_size;
    const float* x0 = (const float*)d_in[0];
    const float* c0 = (const float*)d_in[1];
    const float* w1 = (const float*)d_in[2];  const float* b1 = (const float*)d_in[3];
    const float* w2 = (const float*)d_in[4];  const float* b2 = (const float*)d_in[5];
    const float* w3 = (const float*)d_in[6];  const float* b3 = (const float*)d_in[7];
    const float* w4 = (const float*)d_in[8];  const float* b4 = (const float*)d_in[9];
    const float* w5 = (const float*)d_in[10]; const float* b5 = (const float*)d_in[11];
    const float* w6 = (const float*)d_in[12]; const float* b6 = (const float*)d_in[13];
    const float* w7 = (const float*)d_in[14]; const float* b7 = (const float*)d_in[15];

    float* ws = (float*)d_ws;
    const size_t S512 = 8ull * 2 * 512 * 512;
    const size_t S256 = 8ull * 2 * 256 * 256;
    const size_t S128 = 8ull * 2 * 128 * 128;
    const size_t S64  = 8ull * 2 * 64  * 64;

    float* X1x = ws;            float* X1c = ws + S512;
    float* Ax  = ws + 2 * S512; float* Ac  = ws + 3 * S512;
    float* Bx  = ws + 4 * S512; float* Bc  = ws + 5 * S512;
    float* x23x = Ax;               float* x23c = Ax + S256;
    float* x2x  = Ax + 2 * S256;    float* x2c  = Ax + 3 * S256;
    float* p1x  = Ax + 4 * S256;    float* p1c  = Ax + 5 * S256;
    float* qx   = Ax + 6 * S256;    float* qc   = Ax + 7 * S256;
    float* x3x  = Bx;               float* x3c  = Bx + S128;
    float* p2x  = Bx + 2 * S128;    float* p2c  = Bx + 3 * S128;
    float* x34x = Bx + 4 * S128;    float* x34c = Bx + 5 * S128;
    float* p3x  = Bx + 6 * S128;            float* p3c = Bx + 6 * S128 + S64;
    float* x4x  = Bx + 6 * S128 + 2 * S64;  float* x4c = Bx + 6 * S128 + 3 * S64;

    // K1: fused enc1+enc2 @512 -> (Bx,Bc). NOTE: x3..x4 overlay Bx region is
    // only used AFTER Bx is consumed by K2, so reuse is safe... but Bx region
    // here is ws+4*S512 while small buffers overlay Bx too -> keep order:
    // K2 consumes Bx before K5 writes x3 into the same region.
    enc12_fused<<<dim3(8, 32, 8), 256, 0, stream>>>(
        x0, c0, w1, b1, w2, b2, Bx, Bc);
    // K2: enc3 @512 + pool -> X1 (skip), p1 @256
    nconv_tiled<2, 5, 9, true, true><<<dim3(8, 32, 8), 256, 0, stream>>>(
        Bx, Bc, w3, b3, X1x, X1c, p1x, p1c);
    // K3: enc4 @256 -> q
    nconv_tiled<2, 5, 8, true, false><<<dim3(4, 16, 8), 256, 0, stream>>>(
        p1x, p1c, w2, b2, qx, qc, nullptr, nullptr);
    // K4: enc5 @256 + pool -> x2, p2
    nconv_tiled<2, 5, 8, true, true><<<dim3(4, 16, 8), 256, 0, stream>>>(
        qx, qc, w3, b3, x2x, x2c, p2x, p2c);
    // K5: @128 + pool -> x3, p3
    nconv_tiled<2, 5, 7, true, true><<<dim3(2, 8, 8), 256, 0, stream>>>(
        p2x, p2c, w2, b2, x3x, x3c, p3x, p3c);
    // K6: @64 -> x4
    nconv_tiled<2, 5, 6, true, false><<<dim3(1, 4, 8), 256, 0, stream>>>(
        p3x, p3c, w2, b2, x4x, x4c, nullptr, nullptr);
    // K7: cat @128 -> x34
    nconv_cat_tiled<false, 7, false><<<dim3(2, 8, 8), 256, 0, stream>>>(
        x3x, x3c, x4x, x4c, w4, b4, x34x, x34c, nullptr, nullptr);
    // K8: cat @256 -> x23
    nconv_cat_tiled<false, 8, false><<<dim3(4, 16, 8), 256, 0, stream>>>(
        x2x, x2c, x34x, x34c, w5, b5, x23x, x23c, nullptr, nullptr);
    // K9: cat @512 + final 1x1 -> d_out
    nconv_cat_tiled<true, 9, true><<<dim3(8, 32, 8), 256, 0, stream>>>(
        X1x, X1c, x23x, x23c, w6, b6, (float*)d_out, nullptr, w7, b7);
}